// Round 2
// baseline (13396.477 us; speedup 1.0000x reference)
//
#include <hip/hip_runtime.h>
#include <hip/hip_bf16.h>
#include <math.h>

// Problem constants
#define BB 16
#define TT 512
#define FF 40
#define CC 256
#define HH 256
#define GG 768   // 3*H
#define NB 16

// Workspace layout (float offsets). gi aliases out1 (out1 dead after conv2).
#define O_OUT1 0u                       // [b][h][c][8]  16*512*256*8 = 16777216
#define O_GI   0u                       // [s][b][768]   6291456 (aliases out1)
#define O_OUT2 16777216u                // [b][h][c][2]  4194304  (dead after conv3; cnt reuses it)
#define O_OUT3 20971520u                // [b][h][c]     2097152  (== feats[b][t][c])
#define O_W2T  23068672u                // [ci*25+kh*5+kw][co] 1638400
#define O_W3T  24707072u                // 1638400
#define O_WIHT 26345472u                // [c][g] 196608
#define O_HBUF 26542080u                // 2 * 16*256 = 8192
#define O_CNT  O_OUT2                   // 1 uint barrier counter (aliases dead out2)
// total 26550272 floats = 106.2 MB (same footprint as R0)

// ---------------- weight transposes ----------------
__global__ void transpose_w_kernel(const float* __restrict__ w, float* __restrict__ wt) {
    // w[co][r] (r = ci*25+kh*5+kw, 6400) -> wt[r*256 + co]
    int e = blockIdx.x * 256 + threadIdx.x;   // e = r*256+co, grid 6400
    int r = e >> 8, co = e & 255;
    wt[e] = w[co * 6400 + r];
}

__global__ void transpose_wih_kernel(const float* __restrict__ wih, float* __restrict__ wiht) {
    int g = blockIdx.x;          // 768
    int c = threadIdx.x;         // 256
    wiht[c * 768 + g] = wih[g * 256 + c];
}

// ---------------- conv block 1 ----------------
// x (16,512,40) -> out1 [b][h][c][8]
__global__ __launch_bounds__(256) void conv1_kernel(
    const float* __restrict__ x, const float* __restrict__ w1,
    const float* __restrict__ b1, const float* __restrict__ g1,
    const float* __restrict__ bt1, const float* __restrict__ m1,
    const float* __restrict__ v1, float* __restrict__ out1) {
    int h = blockIdx.x;          // 512
    int b = blockIdx.y;          // 16
    int c = threadIdx.x;         // 256
    __shared__ float xs[5][44];
    int t = threadIdx.x;
    if (t < 220) {
        int rr = t / 44, cc = t % 44;
        int hh = h + rr - 2, ww = cc - 2;
        float v = 0.f;
        if (hh >= 0 && hh < TT && ww >= 0 && ww < FF) v = x[(b * TT + hh) * FF + ww];
        xs[rr][cc] = v;
    }
    __syncthreads();
    float wr[25];
#pragma unroll
    for (int i = 0; i < 25; ++i) wr[i] = w1[c * 25 + i];
    float sc = g1[c] * rsqrtf(v1[c] + 1e-5f);
    float sh = (b1[c] - m1[c]) * sc + bt1[c];
    float conv[40];
#pragma unroll
    for (int w = 0; w < 40; ++w) conv[w] = 0.f;
#pragma unroll
    for (int kh = 0; kh < 5; ++kh) {
        float rr[44];
#pragma unroll
        for (int i = 0; i < 44; ++i) rr[i] = xs[kh][i];
#pragma unroll
        for (int kw = 0; kw < 5; ++kw) {
            float wv = wr[kh * 5 + kw];
#pragma unroll
            for (int w = 0; w < 40; ++w) conv[w] += rr[w + kw] * wv;
        }
    }
    float* op = out1 + (((size_t)(b * TT + h) * CC) + c) * 8;
#pragma unroll
    for (int j = 0; j < 8; ++j) {
        float m = 0.f;   // relu folded into pool (max with 0)
#pragma unroll
        for (int p = 0; p < 5; ++p) m = fmaxf(m, conv[j * 5 + p] * sc + sh);
        op[j] = m;
    }
}

// ---------------- conv block 2 ----------------
// out1 [b][h][ci][8] -> out2 [b][h][co][2]
__global__ __launch_bounds__(256) void conv2_kernel(
    const float* __restrict__ in, const float* __restrict__ w2t,
    const float* __restrict__ b2, const float* __restrict__ g2,
    const float* __restrict__ bt2, const float* __restrict__ m2,
    const float* __restrict__ v2, float* __restrict__ out2) {
    int htile = blockIdx.x;                 // 128
    int b = blockIdx.y;                     // 16
    int co = blockIdx.z * 64 + (threadIdx.x & 63);
    int h = htile * 4 + (threadIdx.x >> 6);
    float acc[8];
#pragma unroll
    for (int w = 0; w < 8; ++w) acc[w] = 0.f;
    for (int ci = 0; ci < CC; ++ci) {
        const float* wb = w2t + (size_t)ci * 25 * 256 + co;
#pragma unroll
        for (int kh = 0; kh < 5; ++kh) {
            int hh = h + kh - 2;
            float4 ra, rb;
            if (hh >= 0 && hh < TT) {
                const float4* ip = (const float4*)(in + (((size_t)(b * TT + hh) * CC) + ci) * 8);
                ra = ip[0]; rb = ip[1];
            } else {
                ra = make_float4(0.f, 0.f, 0.f, 0.f); rb = ra;
            }
            float rin[8] = {ra.x, ra.y, ra.z, ra.w, rb.x, rb.y, rb.z, rb.w};
#pragma unroll
            for (int kw = 0; kw < 5; ++kw) {
                float wv = wb[(kh * 5 + kw) * 256];
#pragma unroll
                for (int w = 0; w < 8; ++w) {
                    int idx = w + kw - 2;
                    if (idx >= 0 && idx < 8) acc[w] += rin[idx] * wv;
                }
            }
        }
    }
    float sc = g2[co] * rsqrtf(v2[co] + 1e-5f);
    float sh = (b2[co] - m2[co]) * sc + bt2[co];
    float p0 = 0.f, p1 = 0.f;
#pragma unroll
    for (int w = 0; w < 4; ++w) p0 = fmaxf(p0, acc[w] * sc + sh);
#pragma unroll
    for (int w = 4; w < 8; ++w) p1 = fmaxf(p1, acc[w] * sc + sh);
    float2* op = (float2*)(out2 + (((size_t)(b * TT + h) * CC) + co) * 2);
    *op = make_float2(p0, p1);
}

// ---------------- conv block 3 ----------------
// out2 [b][h][ci][2] -> out3 [b][h][co]  (== feats[b][t][c])
__global__ __launch_bounds__(256) void conv3_kernel(
    const float* __restrict__ in, const float* __restrict__ w3t,
    const float* __restrict__ b3, const float* __restrict__ g3,
    const float* __restrict__ bt3, const float* __restrict__ m3,
    const float* __restrict__ v3, float* __restrict__ out3) {
    int htile = blockIdx.x;
    int b = blockIdx.y;
    int co = blockIdx.z * 64 + (threadIdx.x & 63);
    int h = htile * 4 + (threadIdx.x >> 6);
    float a0 = 0.f, a1 = 0.f;
    for (int ci = 0; ci < CC; ++ci) {
        const float* wb = w3t + (size_t)ci * 25 * 256 + co;
#pragma unroll
        for (int kh = 0; kh < 5; ++kh) {
            int hh = h + kh - 2;
            float i0 = 0.f, i1 = 0.f;
            if (hh >= 0 && hh < TT) {
                float2 rv = *(const float2*)(in + (((size_t)(b * TT + hh) * CC) + ci) * 2);
                i0 = rv.x; i1 = rv.y;
            }
            float wv1 = wb[(kh * 5 + 1) * 256];
            float wv2 = wb[(kh * 5 + 2) * 256];
            float wv3 = wb[(kh * 5 + 3) * 256];
            a0 += i0 * wv2 + i1 * wv3;
            a1 += i0 * wv1 + i1 * wv2;
        }
    }
    float sc = g3[co] * rsqrtf(v3[co] + 1e-5f);
    float sh = (b3[co] - m3[co]) * sc + bt3[co];
    float r0 = fmaxf(0.f, a0 * sc + sh);
    float r1 = fmaxf(0.f, a1 * sc + sh);
    out3[((size_t)(b * TT + h) * CC) + co] = fmaxf(r0, r1);
}

// ---------------- gi_all GEMM ----------------
// gi[s][b][g] = b_ih[g] + sum_c feats[b*TT+s][c] * w_iht[c][g]
// (stored s-major so each GRU step reads one contiguous 48 KB slice)
__global__ __launch_bounds__(256) void gi_kernel(
    const float* __restrict__ feats, const float* __restrict__ wiht,
    const float* __restrict__ bih, float* __restrict__ gi) {
    int bt0 = blockIdx.x * 16;            // 512 blocks
    int g = blockIdx.y * 256 + threadIdx.x;  // 3 groups
    float acc[16];
    float bv = bih[g];
#pragma unroll
    for (int i = 0; i < 16; ++i) acc[i] = bv;
    for (int c = 0; c < CC; ++c) {
        float wv = wiht[c * GG + g];
#pragma unroll
        for (int i = 0; i < 16; ++i) acc[i] += feats[(size_t)(bt0 + i) * CC + c] * wv;
    }
#pragma unroll
    for (int i = 0; i < 16; ++i) {
        int bt = bt0 + i;                 // bt = b*TT + s
        int b = bt >> 9, s = bt & 511;
        gi[((size_t)s * 16 + b) * GG + g] = acc[i];
    }
}

// ---------------- persistent GRU scan ----------------
// 16 blocks (co-resident on 256 CUs). Block j owns h columns [j*16, j*16+16).
// w_hh slice staged in LDS ONCE; 512 steps with a device-scope grid barrier.
__global__ __launch_bounds__(256) void gru_scan_kernel(
    const float* __restrict__ gi, const float* __restrict__ whh,
    const float* __restrict__ bhh, const float* __restrict__ wcls,
    const float* __restrict__ bcls, float* __restrict__ hbuf,
    float* __restrict__ out, unsigned* __restrict__ cnt) {
    int j = blockIdx.x;       // 0..15
    int t = threadIdx.x;      // 0..255
    __shared__ float lds_w[48 * 260];   // rows [0,16)=r,[16,32)=z,[32,48)=n; stride 260
    __shared__ float lds_hn[16 * 17];
    __shared__ float lds_wcls[16][16];

    // stage this block's 48 w_hh rows (48 KB) into LDS once
#pragma unroll
    for (int i = 0; i < 12; ++i) {
        int q = t + i * 256;              // 3072 float4 total
        int row = q >> 6, col4 = q & 63;
        int slice = row >> 4, within = row & 15;
        int g = slice * 256 + j * 16 + within;
        float4 wv = ((const float4*)whh)[g * 64 + col4];
        *(float4*)&lds_w[row * 260 + col4 * 4] = wv;
    }
    // stage classifier slice: lds_wcls[nb][c2] = wcls[nb][j*16+c2]
    lds_wcls[t >> 4][t & 15] = wcls[(t >> 4) * 256 + j * 16 + (t & 15)];
    __syncthreads();

    int b = t & 15, c = t >> 4;
    int col = j * 16 + c;
    float bh0 = bhh[col], bh1 = bhh[256 + col], bh2 = bhh[512 + col];
    float clsb = (j == 0) ? bcls[t >> 4] : 0.f;

    for (int s = 0; s < TT; ++s) {
        const float* hin = hbuf + (size_t)(s & 1) * (BB * HH);
        float* hout = hbuf + (size_t)((s + 1) & 1) * (BB * HH);

        float a0 = bh0, a1 = bh1, a2 = bh2;
        const float4* hv4 = (const float4*)hin;
#pragma unroll 8
        for (int kq = 0; kq < 64; ++kq) {
            float4 hv = hv4[b * 64 + kq];
            float4 w0 = *(const float4*)&lds_w[c * 260 + kq * 4];
            float4 w1 = *(const float4*)&lds_w[(16 + c) * 260 + kq * 4];
            float4 w2 = *(const float4*)&lds_w[(32 + c) * 260 + kq * 4];
            a0 += hv.x * w0.x + hv.y * w0.y + hv.z * w0.z + hv.w * w0.w;
            a1 += hv.x * w1.x + hv.y * w1.y + hv.z * w1.z + hv.w * w1.w;
            a2 += hv.x * w2.x + hv.y * w2.y + hv.z * w2.z + hv.w * w2.w;
        }
        const float* gp = gi + ((size_t)s * 16 + b) * GG;
        float r = 1.f / (1.f + expf(-(gp[col] + a0)));
        float z = 1.f / (1.f + expf(-(gp[256 + col] + a1)));
        float n = tanhf(gp[512 + col] + r * a2);
        float hold = hin[b * 256 + col];
        float hnew = (1.f - z) * n + z * hold;
        hout[b * 256 + col] = hnew;
        lds_hn[b * 17 + c] = hnew;
        __syncthreads();                    // lds_hn complete for this block

        // classifier partial: block j contributes its 16 columns
        int b2 = t & 15, nb = t >> 4;
        float acc = clsb;
#pragma unroll
        for (int c2 = 0; c2 < 16; ++c2)
            acc += lds_hn[b2 * 17 + c2] * lds_wcls[nb][c2];
        atomicAdd(&out[((size_t)b2 * TT + s) * NB + nb], acc);

        // ---- device-scope grid barrier ----
        // Safety: writing hbuf[(s+1)&1] next step only happens after ALL blocks
        // passed barrier(s), i.e. finished reading it this step.
        __threadfence();                    // release: drain hout stores device-wide
        __syncthreads();
        if (t == 0) {
            __hip_atomic_fetch_add(cnt, 1u, __ATOMIC_RELEASE, __HIP_MEMORY_SCOPE_AGENT);
            unsigned target = 16u * (unsigned)(s + 1);
            while (__hip_atomic_load(cnt, __ATOMIC_ACQUIRE, __HIP_MEMORY_SCOPE_AGENT) < target) {
                __builtin_amdgcn_s_sleep(2);
            }
        }
        __syncthreads();
        __threadfence();                    // acquire: invalidate L1 so h reads are fresh
    }
}

extern "C" void kernel_launch(void* const* d_in, const int* in_sizes, int n_in,
                              void* d_out, int out_size, void* d_ws, size_t ws_size,
                              hipStream_t stream) {
    const float* x    = (const float*)d_in[0];
    const float* w1   = (const float*)d_in[1];
    const float* b1   = (const float*)d_in[2];
    const float* g1   = (const float*)d_in[3];
    const float* bt1  = (const float*)d_in[4];
    const float* m1   = (const float*)d_in[5];
    const float* v1   = (const float*)d_in[6];
    const float* w2   = (const float*)d_in[7];
    const float* b2   = (const float*)d_in[8];
    const float* g2   = (const float*)d_in[9];
    const float* bt2  = (const float*)d_in[10];
    const float* m2   = (const float*)d_in[11];
    const float* v2   = (const float*)d_in[12];
    const float* w3   = (const float*)d_in[13];
    const float* b3   = (const float*)d_in[14];
    const float* g3   = (const float*)d_in[15];
    const float* bt3  = (const float*)d_in[16];
    const float* m3   = (const float*)d_in[17];
    const float* v3   = (const float*)d_in[18];
    const float* wih  = (const float*)d_in[19];
    const float* whh  = (const float*)d_in[20];
    const float* bih  = (const float*)d_in[21];
    const float* bhh  = (const float*)d_in[22];
    const float* wcls = (const float*)d_in[23];
    const float* bcls = (const float*)d_in[24];

    float* ws   = (float*)d_ws;
    float* out1 = ws + O_OUT1;
    float* out2 = ws + O_OUT2;
    float* out3 = ws + O_OUT3;
    float* gi   = ws + O_GI;      // aliases out1 (out1 dead after conv2)
    float* w2t  = ws + O_W2T;
    float* w3t  = ws + O_W3T;
    float* wiht = ws + O_WIHT;
    float* hbuf = ws + O_HBUF;
    unsigned* cnt = (unsigned*)(ws + O_CNT);   // aliases out2 (dead after conv3)
    float* fout = (float*)d_out;

    // zero output accumulator + initial hidden state (both ping-pong buffers)
    hipMemsetAsync(d_out, 0, (size_t)BB * TT * NB * sizeof(float), stream);
    hipMemsetAsync(hbuf, 0, (size_t)2 * BB * HH * sizeof(float), stream);

    // weight transposes
    transpose_w_kernel<<<6400, 256, 0, stream>>>(w2, w2t);
    transpose_w_kernel<<<6400, 256, 0, stream>>>(w3, w3t);
    transpose_wih_kernel<<<768, 256, 0, stream>>>(wih, wiht);

    // conv stack
    conv1_kernel<<<dim3(512, 16), 256, 0, stream>>>(x, w1, b1, g1, bt1, m1, v1, out1);
    conv2_kernel<<<dim3(128, 16, 4), 256, 0, stream>>>(out1, w2t, b2, g2, bt2, m2, v2, out2);
    conv3_kernel<<<dim3(128, 16, 4), 256, 0, stream>>>(out2, w3t, b3, g3, bt3, m3, v3, out3);

    // input-to-hidden GEMM (writes over out1 region; conv2 already consumed it)
    gi_kernel<<<dim3(512, 3), 256, 0, stream>>>(out3, wiht, bih, gi);

    // barrier counter: zero AFTER conv3 (cnt aliases out2 region)
    hipMemsetAsync(cnt, 0, sizeof(unsigned), stream);

    // persistent GRU scan: ONE launch for all 512 steps
    gru_scan_kernel<<<16, 256, 0, stream>>>(gi, whh, bhh, wcls, bcls, hbuf, fout, cnt);
}

// Round 3
// 11581.641 us; speedup vs baseline: 1.1567x; 1.1567x over previous
//
#include <hip/hip_runtime.h>
#include <hip/hip_bf16.h>
#include <math.h>

// Problem constants
#define BB 16
#define TT 512
#define FF 40
#define CC 256
#define HH 256
#define GG 768   // 3*H
#define NB 16

// Workspace layout (float offsets). gi aliases out1 (out1 dead after conv2);
// whhT aliases out2 (dead after conv3 — transpose launched after conv3).
#define O_OUT1 0u                       // [b][h][c][8]  16*512*256*8 = 16777216
#define O_GI   0u                       // [s][b][768]   6291456 (aliases out1)
#define O_OUT2 16777216u                // [b][h][c][2]  4194304
#define O_WHHT O_OUT2                   // [k][g] 196608 (aliases dead out2)
#define O_OUT3 20971520u                // [b][h][c]     2097152  (== feats[b][t][c])
#define O_W2T  23068672u                // [ci*25+kh*5+kw][co] 1638400
#define O_W3T  24707072u                // 1638400
#define O_WIHT 26345472u                // [c][g] 196608
// total 26542080 floats = 106.2 MB

// ---------------- weight transposes ----------------
__global__ void transpose_w_kernel(const float* __restrict__ w, float* __restrict__ wt) {
    // w[co][r] (r = ci*25+kh*5+kw, 6400) -> wt[r*256 + co]
    int e = blockIdx.x * 256 + threadIdx.x;   // e = r*256+co, grid 6400
    int r = e >> 8, co = e & 255;
    wt[e] = w[co * 6400 + r];
}

__global__ void transpose_wih_kernel(const float* __restrict__ wih, float* __restrict__ wiht) {
    int g = blockIdx.x;          // 768
    int c = threadIdx.x;         // 256
    wiht[c * 768 + g] = wih[g * 256 + c];
}

__global__ void transpose_whh_kernel(const float* __restrict__ whh, float* __restrict__ whhT) {
    // whh[g][k] (768x256) -> whhT[k*768 + g]; output-coalesced
    int o = blockIdx.x * 256 + threadIdx.x;   // grid 768 -> 196608
    int k = o / GG, g = o % GG;
    whhT[o] = whh[g * HH + k];
}

// ---------------- conv block 1 ----------------
// x (16,512,40) -> out1 [b][h][c][8]
__global__ __launch_bounds__(256) void conv1_kernel(
    const float* __restrict__ x, const float* __restrict__ w1,
    const float* __restrict__ b1, const float* __restrict__ g1,
    const float* __restrict__ bt1, const float* __restrict__ m1,
    const float* __restrict__ v1, float* __restrict__ out1) {
    int h = blockIdx.x;          // 512
    int b = blockIdx.y;          // 16
    int c = threadIdx.x;         // 256
    __shared__ float xs[5][44];
    int t = threadIdx.x;
    if (t < 220) {
        int rr = t / 44, cc = t % 44;
        int hh = h + rr - 2, ww = cc - 2;
        float v = 0.f;
        if (hh >= 0 && hh < TT && ww >= 0 && ww < FF) v = x[(b * TT + hh) * FF + ww];
        xs[rr][cc] = v;
    }
    __syncthreads();
    float wr[25];
#pragma unroll
    for (int i = 0; i < 25; ++i) wr[i] = w1[c * 25 + i];
    float sc = g1[c] * rsqrtf(v1[c] + 1e-5f);
    float sh = (b1[c] - m1[c]) * sc + bt1[c];
    float conv[40];
#pragma unroll
    for (int w = 0; w < 40; ++w) conv[w] = 0.f;
#pragma unroll
    for (int kh = 0; kh < 5; ++kh) {
        float rr[44];
#pragma unroll
        for (int i = 0; i < 44; ++i) rr[i] = xs[kh][i];
#pragma unroll
        for (int kw = 0; kw < 5; ++kw) {
            float wv = wr[kh * 5 + kw];
#pragma unroll
            for (int w = 0; w < 40; ++w) conv[w] += rr[w + kw] * wv;
        }
    }
    float* op = out1 + (((size_t)(b * TT + h) * CC) + c) * 8;
#pragma unroll
    for (int j = 0; j < 8; ++j) {
        float m = 0.f;   // relu folded into pool (max with 0)
#pragma unroll
        for (int p = 0; p < 5; ++p) m = fmaxf(m, conv[j * 5 + p] * sc + sh);
        op[j] = m;
    }
}

// ---------------- conv block 2 ----------------
// out1 [b][h][ci][8] -> out2 [b][h][co][2]
__global__ __launch_bounds__(256) void conv2_kernel(
    const float* __restrict__ in, const float* __restrict__ w2t,
    const float* __restrict__ b2, const float* __restrict__ g2,
    const float* __restrict__ bt2, const float* __restrict__ m2,
    const float* __restrict__ v2, float* __restrict__ out2) {
    int htile = blockIdx.x;                 // 128
    int b = blockIdx.y;                     // 16
    int co = blockIdx.z * 64 + (threadIdx.x & 63);
    int h = htile * 4 + (threadIdx.x >> 6);
    float acc[8];
#pragma unroll
    for (int w = 0; w < 8; ++w) acc[w] = 0.f;
    for (int ci = 0; ci < CC; ++ci) {
        const float* wb = w2t + (size_t)ci * 25 * 256 + co;
#pragma unroll
        for (int kh = 0; kh < 5; ++kh) {
            int hh = h + kh - 2;
            float4 ra, rb;
            if (hh >= 0 && hh < TT) {
                const float4* ip = (const float4*)(in + (((size_t)(b * TT + hh) * CC) + ci) * 8);
                ra = ip[0]; rb = ip[1];
            } else {
                ra = make_float4(0.f, 0.f, 0.f, 0.f); rb = ra;
            }
            float rin[8] = {ra.x, ra.y, ra.z, ra.w, rb.x, rb.y, rb.z, rb.w};
#pragma unroll
            for (int kw = 0; kw < 5; ++kw) {
                float wv = wb[(kh * 5 + kw) * 256];
#pragma unroll
                for (int w = 0; w < 8; ++w) {
                    int idx = w + kw - 2;
                    if (idx >= 0 && idx < 8) acc[w] += rin[idx] * wv;
                }
            }
        }
    }
    float sc = g2[co] * rsqrtf(v2[co] + 1e-5f);
    float sh = (b2[co] - m2[co]) * sc + bt2[co];
    float p0 = 0.f, p1 = 0.f;
#pragma unroll
    for (int w = 0; w < 4; ++w) p0 = fmaxf(p0, acc[w] * sc + sh);
#pragma unroll
    for (int w = 4; w < 8; ++w) p1 = fmaxf(p1, acc[w] * sc + sh);
    float2* op = (float2*)(out2 + (((size_t)(b * TT + h) * CC) + co) * 2);
    *op = make_float2(p0, p1);
}

// ---------------- conv block 3 ----------------
// out2 [b][h][ci][2] -> out3 [b][h][co]  (== feats[b][t][c])
__global__ __launch_bounds__(256) void conv3_kernel(
    const float* __restrict__ in, const float* __restrict__ w3t,
    const float* __restrict__ b3, const float* __restrict__ g3,
    const float* __restrict__ bt3, const float* __restrict__ m3,
    const float* __restrict__ v3, float* __restrict__ out3) {
    int htile = blockIdx.x;
    int b = blockIdx.y;
    int co = blockIdx.z * 64 + (threadIdx.x & 63);
    int h = htile * 4 + (threadIdx.x >> 6);
    float a0 = 0.f, a1 = 0.f;
    for (int ci = 0; ci < CC; ++ci) {
        const float* wb = w3t + (size_t)ci * 25 * 256 + co;
#pragma unroll
        for (int kh = 0; kh < 5; ++kh) {
            int hh = h + kh - 2;
            float i0 = 0.f, i1 = 0.f;
            if (hh >= 0 && hh < TT) {
                float2 rv = *(const float2*)(in + (((size_t)(b * TT + hh) * CC) + ci) * 2);
                i0 = rv.x; i1 = rv.y;
            }
            float wv1 = wb[(kh * 5 + 1) * 256];
            float wv2 = wb[(kh * 5 + 2) * 256];
            float wv3 = wb[(kh * 5 + 3) * 256];
            a0 += i0 * wv2 + i1 * wv3;
            a1 += i0 * wv1 + i1 * wv2;
        }
    }
    float sc = g3[co] * rsqrtf(v3[co] + 1e-5f);
    float sh = (b3[co] - m3[co]) * sc + bt3[co];
    float r0 = fmaxf(0.f, a0 * sc + sh);
    float r1 = fmaxf(0.f, a1 * sc + sh);
    out3[((size_t)(b * TT + h) * CC) + co] = fmaxf(r0, r1);
}

// ---------------- gi_all GEMM ----------------
// gi[s][b][g] = b_ih[g] + sum_c feats[b*TT+s][c] * w_iht[c][g]
__global__ __launch_bounds__(256) void gi_kernel(
    const float* __restrict__ feats, const float* __restrict__ wiht,
    const float* __restrict__ bih, float* __restrict__ gi) {
    int bt0 = blockIdx.x * 16;            // 512 blocks
    int g = blockIdx.y * 256 + threadIdx.x;  // 3 groups
    float acc[16];
    float bv = bih[g];
#pragma unroll
    for (int i = 0; i < 16; ++i) acc[i] = bv;
    for (int c = 0; c < CC; ++c) {
        float wv = wiht[c * GG + g];
#pragma unroll
        for (int i = 0; i < 16; ++i) acc[i] += feats[(size_t)(bt0 + i) * CC + c] * wv;
    }
#pragma unroll
    for (int i = 0; i < 16; ++i) {
        int bt = bt0 + i;                 // bt = b*TT + s
        int b = bt >> 9, s = bt & 511;
        gi[((size_t)s * 16 + b) * GG + g] = acc[i];
    }
}

// ---------------- batch-parallel GRU scan ----------------
// 16 independent blocks, one per batch element. NO inter-block communication:
// h (256 floats) lives in this block's LDS; w_hh^T streams from the XCD-local
// L2 every step (768 KB/step/CU — the designed bottleneck). Classifier is
// block-local: w_cls slice register-resident, LDS tree reduce, direct stores.
__global__ __launch_bounds__(256) void gru_batch_kernel(
    const float* __restrict__ gi, const float* __restrict__ whhT,
    const float* __restrict__ bhh, const float* __restrict__ wcls,
    const float* __restrict__ bcls, float* __restrict__ out) {
    int b = blockIdx.x;       // 16
    int t = threadIdx.x;      // 256; thread t owns gate column c = t
    __shared__ float hs[HH];
    __shared__ float red[16 * 17];
    int c = t;
    float bh0 = bhh[c], bh1 = bhh[HH + c], bh2 = bhh[2 * HH + c];
    // classifier slice in registers: thread (nb=t&15, q=t>>4) holds wcls[nb][q*16..q*16+16)
    int nb = t & 15, q = t >> 4;
    float wreg[16];
#pragma unroll
    for (int k = 0; k < 16; ++k) wreg[k] = wcls[nb * HH + q * 16 + k];
    float cb = bcls[nb];      // for t<16, nb == t
    hs[c] = 0.f;
    __syncthreads();

    for (int s = 0; s < TT; ++s) {
        const float* gp = gi + ((size_t)s * BB + b) * GG;
        float a0 = bh0, a1 = bh1, a2 = bh2;
        const float* wp = whhT + c;
#pragma unroll 4
        for (int k4 = 0; k4 < 64; ++k4) {
            float4 hk = *(const float4*)&hs[k4 * 4];     // wave-broadcast b128
            const float* w = wp + (size_t)k4 * 4 * GG;
            a0 += hk.x * w[0]          + hk.y * w[GG]
                + hk.z * w[2 * GG]     + hk.w * w[3 * GG];
            a1 += hk.x * w[HH]         + hk.y * w[GG + HH]
                + hk.z * w[2 * GG + HH] + hk.w * w[3 * GG + HH];
            a2 += hk.x * w[2 * HH]     + hk.y * w[GG + 2 * HH]
                + hk.z * w[2 * GG + 2 * HH] + hk.w * w[3 * GG + 2 * HH];
        }
        float r = 1.f / (1.f + expf(-(gp[c] + a0)));
        float z = 1.f / (1.f + expf(-(gp[HH + c] + a1)));
        float n = tanhf(gp[2 * HH + c] + r * a2);
        float hold = hs[c];
        float hnew = (1.f - z) * n + z * hold;
        __syncthreads();                  // all hs reads of this step done
        hs[c] = hnew;
        __syncthreads();                  // new h visible block-wide

        // classifier: out[b][s][nb] = bcls[nb] + sum_c h[c]*wcls[nb][c]
        float acc = 0.f;
        const float4* hq = (const float4*)&hs[q * 16];
#pragma unroll
        for (int k4 = 0; k4 < 4; ++k4) {
            float4 hv = hq[k4];
            acc += hv.x * wreg[k4 * 4]     + hv.y * wreg[k4 * 4 + 1]
                 + hv.z * wreg[k4 * 4 + 2] + hv.w * wreg[k4 * 4 + 3];
        }
        red[q * 17 + nb] = acc;
        __syncthreads();
        if (t < 16) {
            float o = cb;
#pragma unroll
            for (int qq = 0; qq < 16; ++qq) o += red[qq * 17 + t];
            out[((size_t)b * TT + s) * NB + t] = o;
        }
    }
}

extern "C" void kernel_launch(void* const* d_in, const int* in_sizes, int n_in,
                              void* d_out, int out_size, void* d_ws, size_t ws_size,
                              hipStream_t stream) {
    const float* x    = (const float*)d_in[0];
    const float* w1   = (const float*)d_in[1];
    const float* b1   = (const float*)d_in[2];
    const float* g1   = (const float*)d_in[3];
    const float* bt1  = (const float*)d_in[4];
    const float* m1   = (const float*)d_in[5];
    const float* v1   = (const float*)d_in[6];
    const float* w2   = (const float*)d_in[7];
    const float* b2   = (const float*)d_in[8];
    const float* g2   = (const float*)d_in[9];
    const float* bt2  = (const float*)d_in[10];
    const float* m2   = (const float*)d_in[11];
    const float* v2   = (const float*)d_in[12];
    const float* w3   = (const float*)d_in[13];
    const float* b3   = (const float*)d_in[14];
    const float* g3   = (const float*)d_in[15];
    const float* bt3  = (const float*)d_in[16];
    const float* m3   = (const float*)d_in[17];
    const float* v3   = (const float*)d_in[18];
    const float* wih  = (const float*)d_in[19];
    const float* whh  = (const float*)d_in[20];
    const float* bih  = (const float*)d_in[21];
    const float* bhh  = (const float*)d_in[22];
    const float* wcls = (const float*)d_in[23];
    const float* bcls = (const float*)d_in[24];

    float* ws   = (float*)d_ws;
    float* out1 = ws + O_OUT1;
    float* out2 = ws + O_OUT2;
    float* out3 = ws + O_OUT3;
    float* gi   = ws + O_GI;      // aliases out1 (out1 dead after conv2)
    float* whhT = ws + O_WHHT;    // aliases out2 (dead after conv3)
    float* w2t  = ws + O_W2T;
    float* w3t  = ws + O_W3T;
    float* wiht = ws + O_WIHT;
    float* fout = (float*)d_out;

    // weight transposes (conv + gi; whh transpose must wait for conv3)
    transpose_w_kernel<<<6400, 256, 0, stream>>>(w2, w2t);
    transpose_w_kernel<<<6400, 256, 0, stream>>>(w3, w3t);
    transpose_wih_kernel<<<768, 256, 0, stream>>>(wih, wiht);

    // conv stack
    conv1_kernel<<<dim3(512, 16), 256, 0, stream>>>(x, w1, b1, g1, bt1, m1, v1, out1);
    conv2_kernel<<<dim3(128, 16, 4), 256, 0, stream>>>(out1, w2t, b2, g2, bt2, m2, v2, out2);
    conv3_kernel<<<dim3(128, 16, 4), 256, 0, stream>>>(out2, w3t, b3, g3, bt3, m3, v3, out3);

    // whh transpose into the (now dead) out2 region
    transpose_whh_kernel<<<768, 256, 0, stream>>>(whh, whhT);

    // input-to-hidden GEMM (writes over out1 region; conv2 already consumed it)
    gi_kernel<<<dim3(512, 3), 256, 0, stream>>>(out3, wiht, bih, gi);

    // batch-parallel GRU scan: ONE launch, zero inter-block communication
    gru_batch_kernel<<<16, 256, 0, stream>>>(gi, whhT, bhh, wcls, bcls, fout);
}

// Round 4
// 6372.913 us; speedup vs baseline: 2.1021x; 1.8173x over previous
//
#include <hip/hip_runtime.h>
#include <hip/hip_bf16.h>
#include <math.h>

// Problem constants
#define BB 16
#define TT 512
#define FF 40
#define CC 256
#define HH 256
#define GG 768   // 3*H
#define NB 16

typedef _Float16 f16;
typedef __attribute__((ext_vector_type(8))) _Float16 f16x8;
typedef __attribute__((ext_vector_type(4))) _Float16 f16x4;
typedef __attribute__((ext_vector_type(4))) float f32x4;

// Workspace layout (float offsets). gi aliases out1 (out1 dead after conv2);
// whhT_h aliases out2 (dead after conv3 — convert launched after conv3).
#define O_OUT1 0u                       // [b][h][c][8]  16777216
#define O_GI   0u                       // [s][b][768]   6291456 (aliases out1)
#define O_OUT2 16777216u                // [b][h][c][2]  4194304
#define O_WHHT O_OUT2                   // 196608 halves (aliases dead out2)
#define O_OUT3 20971520u                // [b][h][c]     2097152  (== feats[b][t][c])
#define O_W2P  23068672u                // packed fp16 conv2 weights, 1638400 halves
#define O_W3T  24707072u                // 1638400
#define O_WIHT 26345472u                // [c][g] 196608
// total 26542080 floats = 106.2 MB

// ---------------- weight prep ----------------
__global__ void transpose_w_kernel(const float* __restrict__ w, float* __restrict__ wt) {
    // w[co][r] (r = ci*25+kh*5+kw, 6400) -> wt[r*256 + co]
    int e = blockIdx.x * 256 + threadIdx.x;
    int r = e >> 8, co = e & 255;
    wt[e] = w[co * 6400 + r];
}

__global__ void transpose_wih_kernel(const float* __restrict__ wih, float* __restrict__ wiht) {
    int g = blockIdx.x;          // 768
    int c = threadIdx.x;         // 256
    wiht[c * 768 + g] = wih[g * 256 + c];
}

__global__ void convert_whh_kernel(const float* __restrict__ whh, f16* __restrict__ whhT_h) {
    // whh[g][k] (768x256) -> whhT_h[k*768 + g] fp16
    int k = blockIdx.x;          // 256
    int g = threadIdx.x;         // 768
    whhT_h[k * GG + g] = (f16)whh[g * HH + k];
}

// Pack conv2 weights into exact MFMA B-fragment order (fp16).
// entry e = (((tap*2+cs)*4+cs4)*16 + ntile4)*64 + lane ; 8 halves per entry.
// B[k][n]: n = ntile4*16 + (lane&15) = co ; k-ci = cs*128 + cs4*32 + (lane>>4)*8 + j
__global__ __launch_bounds__(256) void pack_w2_kernel(const float* __restrict__ w2, f16* __restrict__ w2p) {
    int e = blockIdx.x * 256 + threadIdx.x;     // grid 800 -> 204800 entries
    int lane = e & 63;
    int r1 = e >> 6;
    int ntile4 = r1 & 15;
    int r2 = r1 >> 4;
    int cs4 = r2 & 3;
    int r3 = r2 >> 2;
    int cs = r3 & 1;
    int tap = r3 >> 1;                          // 0..24
    int co = ntile4 * 16 + (lane & 15);
    int ci0 = cs * 128 + cs4 * 32 + (lane >> 4) * 8;
    f16x8 v;
#pragma unroll
    for (int j = 0; j < 8; ++j)
        v[j] = (f16)w2[(size_t)co * 6400 + (ci0 + j) * 25 + tap];
    *(f16x8*)(w2p + (size_t)e * 8) = v;
}

// ---------------- conv block 1 (fp32, unchanged) ----------------
__global__ __launch_bounds__(256) void conv1_kernel(
    const float* __restrict__ x, const float* __restrict__ w1,
    const float* __restrict__ b1, const float* __restrict__ g1,
    const float* __restrict__ bt1, const float* __restrict__ m1,
    const float* __restrict__ v1, float* __restrict__ out1) {
    int h = blockIdx.x;          // 512
    int b = blockIdx.y;          // 16
    int c = threadIdx.x;         // 256
    __shared__ float xs[5][44];
    int t = threadIdx.x;
    if (t < 220) {
        int rr = t / 44, cc = t % 44;
        int hh = h + rr - 2, ww = cc - 2;
        float v = 0.f;
        if (hh >= 0 && hh < TT && ww >= 0 && ww < FF) v = x[(b * TT + hh) * FF + ww];
        xs[rr][cc] = v;
    }
    __syncthreads();
    float wr[25];
#pragma unroll
    for (int i = 0; i < 25; ++i) wr[i] = w1[c * 25 + i];
    float sc = g1[c] * rsqrtf(v1[c] + 1e-5f);
    float sh = (b1[c] - m1[c]) * sc + bt1[c];
    float conv[40];
#pragma unroll
    for (int w = 0; w < 40; ++w) conv[w] = 0.f;
#pragma unroll
    for (int kh = 0; kh < 5; ++kh) {
        float rr[44];
#pragma unroll
        for (int i = 0; i < 44; ++i) rr[i] = xs[kh][i];
#pragma unroll
        for (int kw = 0; kw < 5; ++kw) {
            float wv = wr[kh * 5 + kw];
#pragma unroll
            for (int w = 0; w < 40; ++w) conv[w] += rr[w + kw] * wv;
        }
    }
    float* op = out1 + (((size_t)(b * TT + h) * CC) + c) * 8;
#pragma unroll
    for (int j = 0; j < 8; ++j) {
        float m = 0.f;
#pragma unroll
        for (int p = 0; p < 5; ++p) m = fmaxf(m, conv[j * 5 + p] * sc + sh);
        op[j] = m;
    }
}

// ---------------- conv block 2: fp16 MFMA implicit GEMM ----------------
// Block: (htile, b). Output tile M=64 (8 h x 8 w), N=256 co (4 waves x 64).
// K = 25 taps x 256 ci, MFMA 16x16x32_f16. A staged in LDS with w-zero-pad.
// A[m][k]: m = dh*8+w, k = ci; element = in[b][h0+dh+kh-2][ci][w+kw-2].
__global__ __launch_bounds__(256) void conv2_mfma_kernel(
    const float* __restrict__ in, const f16* __restrict__ w2p,
    const float* __restrict__ b2, const float* __restrict__ g2,
    const float* __restrict__ bt2, const float* __restrict__ m2,
    const float* __restrict__ v2, float* __restrict__ out2) {
    int htile = blockIdx.x;                 // 64
    int b = blockIdx.y;                     // 16
    int h0 = htile * 8;
    int t = threadIdx.x;
    int lane = t & 63, wid = t >> 6;
    int m16 = lane & 15, kq = lane >> 4;    // kq also = C/D quad q4

    // lds_a[row 12][wp 12][ci 136 (128 + 8 pad)] halves; rows h'=h0-2..h0+9, wp = w'+2
    __shared__ f16 lds_a[12 * 12 * 136];    // 39168 B

    // zero once (pads stay zero; staging overwrites only wp 2..9, ci<128)
#pragma unroll
    for (int i = 0; i < 39; ++i) {
        int idx = t + i * 256;
        if (idx < 9792) ((unsigned*)lds_a)[idx] = 0u;
    }
    __syncthreads();

    f32x4 acc[4][4];
#pragma unroll
    for (int mf = 0; mf < 4; ++mf)
#pragma unroll
        for (int nf = 0; nf < 4; ++nf) acc[mf][nf] = (f32x4)(0.f);

    for (int cs = 0; cs < 2; ++cs) {        // ci chunk of 128
        if (cs) __syncthreads();            // drain prev chunk's reads
        // ---- stage: 12 rows x 32 ci-quads; each task: 8 float4 loads -> 8 half4 stores
#pragma unroll
        for (int i = 0; i < 2; ++i) {
            int qq = t + i * 256;
            if (qq < 384) {
                int row = qq >> 5, ciq = qq & 31;
                int hp = h0 - 2 + row;
                float fv[32];               // fv[cc*8 + w]
                if (hp >= 0 && hp < TT) {
                    const float4* src = (const float4*)(in + (((size_t)(b * TT + hp) * CC) + cs * 128 + ciq * 4) * 8);
#pragma unroll
                    for (int cc = 0; cc < 4; ++cc) {
                        float4 u0 = src[cc * 2], u1 = src[cc * 2 + 1];
                        fv[cc * 8 + 0] = u0.x; fv[cc * 8 + 1] = u0.y; fv[cc * 8 + 2] = u0.z; fv[cc * 8 + 3] = u0.w;
                        fv[cc * 8 + 4] = u1.x; fv[cc * 8 + 5] = u1.y; fv[cc * 8 + 6] = u1.z; fv[cc * 8 + 7] = u1.w;
                    }
                } else {
#pragma unroll
                    for (int z = 0; z < 32; ++z) fv[z] = 0.f;
                }
#pragma unroll
                for (int w = 0; w < 8; ++w) {
                    f16x4 hv = { (f16)fv[0 * 8 + w], (f16)fv[1 * 8 + w], (f16)fv[2 * 8 + w], (f16)fv[3 * 8 + w] };
                    *(f16x4*)&lds_a[row * 1632 + (w + 2) * 136 + ciq * 4] = hv;
                }
            }
        }
        __syncthreads();
        // ---- K loop: 25 taps x 4 sub-chunks of 32 ci
        for (int kh = 0; kh < 5; ++kh) {
#pragma unroll
            for (int kw = 0; kw < 5; ++kw) {
                int tap = kh * 5 + kw;
#pragma unroll
                for (int cs4 = 0; cs4 < 4; ++cs4) {
                    f16x8 af[4];
#pragma unroll
                    for (int mf = 0; mf < 4; ++mf) {
                        int m = mf * 16 + m16;
                        int row = (m >> 3) + kh;        // dh + kh
                        int wp = (m & 7) + kw;          // w + kw
                        af[mf] = *(const f16x8*)&lds_a[row * 1632 + wp * 136 + cs4 * 32 + kq * 8];
                    }
                    const f16x8* bp = (const f16x8*)w2p
                        + ((size_t)(((tap * 2 + cs) * 4 + cs4) * 16 + wid * 4) * 64 + lane);
#pragma unroll
                    for (int nf = 0; nf < 4; ++nf) {
                        f16x8 bf = bp[nf * 64];
#pragma unroll
                        for (int mf = 0; mf < 4; ++mf)
                            acc[mf][nf] = __builtin_amdgcn_mfma_f32_16x16x32_f16(af[mf], bf, acc[mf][nf], 0, 0, 0);
                    }
                }
            }
        }
    }

    // ---- epilogue: BN + ReLU + pool4. D: col=lane&15 (co), row=kq*4+reg (m).
    // Thread's 4 regs of frag mf = the 4 w of pool group (dh=mf*2+(kq>>1), wout=kq&1).
#pragma unroll
    for (int nf = 0; nf < 4; ++nf) {
        int co = wid * 64 + nf * 16 + m16;
        float sc = g2[co] * rsqrtf(v2[co] + 1e-5f);
        float sh = (b2[co] - m2[co]) * sc + bt2[co];
#pragma unroll
        for (int mf = 0; mf < 4; ++mf) {
            f32x4 v = acc[mf][nf];
            float p = 0.f;
            p = fmaxf(p, v[0] * sc + sh);
            p = fmaxf(p, v[1] * sc + sh);
            p = fmaxf(p, v[2] * sc + sh);
            p = fmaxf(p, v[3] * sc + sh);
            int dh = mf * 2 + (kq >> 1);
            int wout = kq & 1;
            out2[(((size_t)(b * TT + h0 + dh) * CC) + co) * 2 + wout] = p;
        }
    }
}

// ---------------- conv block 3 (fp32, unchanged) ----------------
__global__ __launch_bounds__(256) void conv3_kernel(
    const float* __restrict__ in, const float* __restrict__ w3t,
    const float* __restrict__ b3, const float* __restrict__ g3,
    const float* __restrict__ bt3, const float* __restrict__ m3,
    const float* __restrict__ v3, float* __restrict__ out3) {
    int htile = blockIdx.x;
    int b = blockIdx.y;
    int co = blockIdx.z * 64 + (threadIdx.x & 63);
    int h = htile * 4 + (threadIdx.x >> 6);
    float a0 = 0.f, a1 = 0.f;
    for (int ci = 0; ci < CC; ++ci) {
        const float* wb = w3t + (size_t)ci * 25 * 256 + co;
#pragma unroll
        for (int kh = 0; kh < 5; ++kh) {
            int hh = h + kh - 2;
            float i0 = 0.f, i1 = 0.f;
            if (hh >= 0 && hh < TT) {
                float2 rv = *(const float2*)(in + (((size_t)(b * TT + hh) * CC) + ci) * 2);
                i0 = rv.x; i1 = rv.y;
            }
            float wv1 = wb[(kh * 5 + 1) * 256];
            float wv2 = wb[(kh * 5 + 2) * 256];
            float wv3 = wb[(kh * 5 + 3) * 256];
            a0 += i0 * wv2 + i1 * wv3;
            a1 += i0 * wv1 + i1 * wv2;
        }
    }
    float sc = g3[co] * rsqrtf(v3[co] + 1e-5f);
    float sh = (b3[co] - m3[co]) * sc + bt3[co];
    float r0 = fmaxf(0.f, a0 * sc + sh);
    float r1 = fmaxf(0.f, a1 * sc + sh);
    out3[((size_t)(b * TT + h) * CC) + co] = fmaxf(r0, r1);
}

// ---------------- gi_all GEMM (fp32, unchanged) ----------------
__global__ __launch_bounds__(256) void gi_kernel(
    const float* __restrict__ feats, const float* __restrict__ wiht,
    const float* __restrict__ bih, float* __restrict__ gi) {
    int bt0 = blockIdx.x * 16;
    int g = blockIdx.y * 256 + threadIdx.x;
    float acc[16];
    float bv = bih[g];
#pragma unroll
    for (int i = 0; i < 16; ++i) acc[i] = bv;
    for (int c = 0; c < CC; ++c) {
        float wv = wiht[c * GG + g];
#pragma unroll
        for (int i = 0; i < 16; ++i) acc[i] += feats[(size_t)(bt0 + i) * CC + c] * wv;
    }
#pragma unroll
    for (int i = 0; i < 16; ++i) {
        int bt = bt0 + i;
        int b = bt >> 9, s = bt & 511;
        gi[((size_t)s * 16 + b) * GG + g] = acc[i];
    }
}

// ---------------- batch-parallel GRU scan, 1024 threads, fp16 weights ----------------
// 16 blocks, one per batch element; zero inter-block communication.
// Thread (c = t&255, ks = t>>8): partial gate dots over k in [ks*64, ks*64+64).
// Weights whhT_h[k][g] fp16 -> 128 B/wave dense coalesced loads, 393 KB/step from L2.
__global__ __launch_bounds__(1024) void gru_batch_kernel(
    const float* __restrict__ gi, const f16* __restrict__ whhT_h,
    const float* __restrict__ bhh, const float* __restrict__ wcls,
    const float* __restrict__ bcls, float* __restrict__ out) {
    int b = blockIdx.x;       // 16
    int t = threadIdx.x;      // 1024
    int c = t & 255, ks = t >> 8;
    __shared__ float hs[HH];
    __shared__ float red[12 * 256];      // [gate*4+ks][c]
    __shared__ float red_cls[16 * 17];
    float bh0 = 0.f, bh1 = 0.f, bh2 = 0.f, cb = 0.f;
    float wreg[16];
    int nb = t & 15, q = (t >> 4) & 15;
    if (t < 256) {
        bh0 = bhh[c]; bh1 = bhh[HH + c]; bh2 = bhh[2 * HH + c];
#pragma unroll
        for (int k = 0; k < 16; ++k) wreg[k] = wcls[nb * HH + q * 16 + k];
        cb = bcls[nb];
        hs[t] = 0.f;
    }
    __syncthreads();

    for (int s = 0; s < TT; ++s) {
        float a0 = 0.f, a1 = 0.f, a2 = 0.f;
#pragma unroll 4
        for (int k4 = 0; k4 < 16; ++k4) {
            int k0 = ks * 64 + k4 * 4;
            float4 hv = *(const float4*)&hs[k0];        // wave-uniform broadcast
            float hvv[4] = { hv.x, hv.y, hv.z, hv.w };
            const f16* r0 = whhT_h + (size_t)k0 * GG + c;
#pragma unroll
            for (int j = 0; j < 4; ++j) {
                const f16* rr = r0 + j * GG;
                a0 += hvv[j] * (float)rr[0];
                a1 += hvv[j] * (float)rr[HH];
                a2 += hvv[j] * (float)rr[2 * HH];
            }
        }
        red[(0 * 4 + ks) * 256 + c] = a0;
        red[(1 * 4 + ks) * 256 + c] = a1;
        red[(2 * 4 + ks) * 256 + c] = a2;
        __syncthreads();                  // B1: all partials in, all hs reads done

        if (t < 256) {
            float s0 = red[0 * 256 + c] + red[1 * 256 + c] + red[2 * 256 + c] + red[3 * 256 + c];
            float s1 = red[4 * 256 + c] + red[5 * 256 + c] + red[6 * 256 + c] + red[7 * 256 + c];
            float s2 = red[8 * 256 + c] + red[9 * 256 + c] + red[10 * 256 + c] + red[11 * 256 + c];
            const float* gp = gi + ((size_t)s * BB + b) * GG;
            float r = 1.f / (1.f + expf(-(gp[c] + bh0 + s0)));
            float z = 1.f / (1.f + expf(-(gp[HH + c] + bh1 + s1)));
            float n = tanhf(gp[2 * HH + c] + r * (bh2 + s2));
            float hold = hs[c];
            hs[c] = (1.f - z) * n + z * hold;
        }
        __syncthreads();                  // B2: new h visible

        if (t < 256) {
            float acc = 0.f;
            const float4* hq = (const float4*)&hs[q * 16];
#pragma unroll
            for (int k4 = 0; k4 < 4; ++k4) {
                float4 hv = hq[k4];
                acc += hv.x * wreg[k4 * 4] + hv.y * wreg[k4 * 4 + 1]
                     + hv.z * wreg[k4 * 4 + 2] + hv.w * wreg[k4 * 4 + 3];
            }
            red_cls[q * 17 + nb] = acc;
        }
        __syncthreads();                  // B3: classifier partials in

        if (t < 16) {
            float o = cb;
#pragma unroll
            for (int qq = 0; qq < 16; ++qq) o += red_cls[qq * 17 + t];
            out[((size_t)b * TT + s) * NB + t] = o;
        }
    }
}

extern "C" void kernel_launch(void* const* d_in, const int* in_sizes, int n_in,
                              void* d_out, int out_size, void* d_ws, size_t ws_size,
                              hipStream_t stream) {
    const float* x    = (const float*)d_in[0];
    const float* w1   = (const float*)d_in[1];
    const float* b1   = (const float*)d_in[2];
    const float* g1   = (const float*)d_in[3];
    const float* bt1  = (const float*)d_in[4];
    const float* m1   = (const float*)d_in[5];
    const float* v1   = (const float*)d_in[6];
    const float* w2   = (const float*)d_in[7];
    const float* b2   = (const float*)d_in[8];
    const float* g2   = (const float*)d_in[9];
    const float* bt2  = (const float*)d_in[10];
    const float* m2   = (const float*)d_in[11];
    const float* v2   = (const float*)d_in[12];
    const float* w3   = (const float*)d_in[13];
    const float* b3   = (const float*)d_in[14];
    const float* g3   = (const float*)d_in[15];
    const float* bt3  = (const float*)d_in[16];
    const float* m3   = (const float*)d_in[17];
    const float* v3   = (const float*)d_in[18];
    const float* wih  = (const float*)d_in[19];
    const float* whh  = (const float*)d_in[20];
    const float* bih  = (const float*)d_in[21];
    const float* bhh  = (const float*)d_in[22];
    const float* wcls = (const float*)d_in[23];
    const float* bcls = (const float*)d_in[24];

    float* ws   = (float*)d_ws;
    float* out1 = ws + O_OUT1;
    float* out2 = ws + O_OUT2;
    float* out3 = ws + O_OUT3;
    float* gi   = ws + O_GI;               // aliases out1 (dead after conv2)
    f16*   w2p  = (f16*)(ws + O_W2P);
    float* w3t  = ws + O_W3T;
    float* wiht = ws + O_WIHT;
    f16*   whhT_h = (f16*)(ws + O_WHHT);   // aliases out2 (dead after conv3)
    float* fout = (float*)d_out;

    // weight prep
    pack_w2_kernel<<<800, 256, 0, stream>>>(w2, w2p);
    transpose_w_kernel<<<6400, 256, 0, stream>>>(w3, w3t);
    transpose_wih_kernel<<<768, 256, 0, stream>>>(wih, wiht);

    // conv stack
    conv1_kernel<<<dim3(512, 16), 256, 0, stream>>>(x, w1, b1, g1, bt1, m1, v1, out1);
    conv2_mfma_kernel<<<dim3(64, 16), 256, 0, stream>>>(out1, w2p, b2, g2, bt2, m2, v2, out2);
    conv3_kernel<<<dim3(128, 16, 4), 256, 0, stream>>>(out2, w3t, b3, g3, bt3, m3, v3, out3);

    // whh fp16 convert into the (now dead) out2 region
    convert_whh_kernel<<<256, 768, 0, stream>>>(whh, whhT_h);

    // input-to-hidden GEMM (writes over out1 region; conv2 already consumed it)
    gi_kernel<<<dim3(512, 3), 256, 0, stream>>>(out3, wiht, bih, gi);

    // batch-parallel GRU scan: ONE launch, zero inter-block communication
    gru_batch_kernel<<<16, 1024, 0, stream>>>(gi, whhT_h, bhh, wcls, bcls, fout);
}

// Round 5
// 4343.992 us; speedup vs baseline: 3.0839x; 1.4671x over previous
//
#include <hip/hip_runtime.h>
#include <hip/hip_bf16.h>
#include <math.h>

// Problem constants
#define BB 16
#define TT 512
#define FF 40
#define CC 256
#define HH 256
#define GG 768   // 3*H
#define NB 16

typedef _Float16 f16;
typedef __attribute__((ext_vector_type(8))) _Float16 f16x8;
typedef __attribute__((ext_vector_type(4))) _Float16 f16x4;
typedef __attribute__((ext_vector_type(4))) float f32x4;

// Workspace layout (float offsets).
// gi aliases out1 (out1 dead after conv2); whhp aliases out2 (packed after conv3).
#define O_OUT1 0u                       // [b][h][c][8]  16777216
#define O_GI   0u                       // [s][b][768]   6291456 (aliases out1)
#define O_OUT2 16777216u                // [b][h][c][2]  4194304
#define O_WHHP O_OUT2                   // 196608 halves (aliases dead out2)
#define O_OUT3 20971520u                // [b][h][c]     2097152  (== feats[b][t][c])
#define O_W2P  23068672u                // packed fp16 conv2 weights, 1638400 halves
#define O_W3P  24707072u                // packed fp16 conv3 weights, 983040 halves (+ wclsp 4096 halves)
#define O_WIHT 26345472u                // [c][g] 196608
// total 26542080 floats = 106.2 MB (unchanged footprint)

// ---------------- weight prep ----------------
__global__ void transpose_wih_kernel(const float* __restrict__ wih, float* __restrict__ wiht) {
    int g = blockIdx.x;          // 768
    int c = threadIdx.x;         // 256
    wiht[c * 768 + g] = wih[g * 256 + c];
}

// conv2 weights -> MFMA B-fragment order (fp16). Layout verified on HW in R3->R4.
// entry e = (((tap*2+cs)*4+cs4)*16 + ntile)*64 + lane ; 8 halves per entry.
__global__ __launch_bounds__(256) void pack_w2_kernel(const float* __restrict__ w2, f16* __restrict__ w2p) {
    int e = blockIdx.x * 256 + threadIdx.x;     // grid 800 -> 204800 entries
    int lane = e & 63;
    int r1 = e >> 6;
    int ntile = r1 & 15;
    int r2 = r1 >> 4;
    int cs4 = r2 & 3;
    int r3 = r2 >> 2;
    int cs = r3 & 1;
    int tap = r3 >> 1;                          // 0..24
    int co = ntile * 16 + (lane & 15);
    int ci0 = cs * 128 + cs4 * 32 + (lane >> 4) * 8;
    f16x8 v;
#pragma unroll
    for (int j = 0; j < 8; ++j)
        v[j] = (f16)w2[(size_t)co * 6400 + (ci0 + j) * 25 + tap];
    *(f16x8*)(w2p + (size_t)e * 8) = v;
}

// conv3 weights: only kw in {1,2,3} can touch the W=2 input -> 15 taps.
// tap15 = kh*3 + (kw-1). Same fragment order as conv2.
__global__ __launch_bounds__(256) void pack_w3_kernel(const float* __restrict__ w3, f16* __restrict__ w3p) {
    int e = blockIdx.x * 256 + threadIdx.x;     // grid 480 -> 122880 entries
    int lane = e & 63;
    int r1 = e >> 6;
    int ntile = r1 & 15;
    int r2 = r1 >> 4;
    int cs4 = r2 & 3;
    int r3 = r2 >> 2;
    int cs = r3 & 1;
    int tap = r3 >> 1;                          // 0..14
    int kh = tap / 3, kw = tap % 3 + 1;
    int co = ntile * 16 + (lane & 15);
    int ci0 = cs * 128 + cs4 * 32 + (lane >> 4) * 8;
    f16x8 v;
#pragma unroll
    for (int j = 0; j < 8; ++j)
        v[j] = (f16)w3[(size_t)co * 6400 + (ci0 + j) * 25 + kh * 5 + kw];
    *(f16x8*)(w3p + (size_t)e * 8) = v;
}

// w_hh -> B-fragment order for the GRU GEMM: entry e = (kf*48 + tile)*64 + lane.
// B[k][g]: g = tile*16 + (lane&15), k = kf*32 + (lane>>4)*8 + j. whh is [g][k] row-major.
__global__ __launch_bounds__(256) void pack_whh_kernel(const float* __restrict__ whh, f16* __restrict__ whhp) {
    int e = blockIdx.x * 256 + threadIdx.x;     // grid 96 -> 24576 entries
    int lane = e & 63;
    int r1 = e >> 6;                            // 0..383
    int tile = r1 % 48, kf = r1 / 48;
    int g = tile * 16 + (lane & 15);
    int k0 = kf * 32 + (lane >> 4) * 8;
    f16x8 v;
#pragma unroll
    for (int j = 0; j < 8; ++j)
        v[j] = (f16)whh[(size_t)g * HH + k0 + j];
    *(f16x8*)(whhp + (size_t)e * 8) = v;
}

// w_cls -> B-fragment order: entry e = kf*64 + lane; B[k=c][n=nb].
__global__ void pack_wcls_kernel(const float* __restrict__ wcls, f16* __restrict__ wclsp) {
    int e = threadIdx.x;                        // 512
    int lane = e & 63, kf = e >> 6;
    int nb = lane & 15;
    int c0 = kf * 32 + (lane >> 4) * 8;
    f16x8 v;
#pragma unroll
    for (int j = 0; j < 8; ++j)
        v[j] = (f16)wcls[nb * HH + c0 + j];
    *(f16x8*)(wclsp + (size_t)e * 8) = v;
}

// ---------------- conv block 1 (fp32, unchanged) ----------------
__global__ __launch_bounds__(256) void conv1_kernel(
    const float* __restrict__ x, const float* __restrict__ w1,
    const float* __restrict__ b1, const float* __restrict__ g1,
    const float* __restrict__ bt1, const float* __restrict__ m1,
    const float* __restrict__ v1, float* __restrict__ out1) {
    int h = blockIdx.x;          // 512
    int b = blockIdx.y;          // 16
    int c = threadIdx.x;         // 256
    __shared__ float xs[5][44];
    int t = threadIdx.x;
    if (t < 220) {
        int rr = t / 44, cc = t % 44;
        int hh = h + rr - 2, ww = cc - 2;
        float v = 0.f;
        if (hh >= 0 && hh < TT && ww >= 0 && ww < FF) v = x[(b * TT + hh) * FF + ww];
        xs[rr][cc] = v;
    }
    __syncthreads();
    float wr[25];
#pragma unroll
    for (int i = 0; i < 25; ++i) wr[i] = w1[c * 25 + i];
    float sc = g1[c] * rsqrtf(v1[c] + 1e-5f);
    float sh = (b1[c] - m1[c]) * sc + bt1[c];
    float conv[40];
#pragma unroll
    for (int w = 0; w < 40; ++w) conv[w] = 0.f;
#pragma unroll
    for (int kh = 0; kh < 5; ++kh) {
        float rr[44];
#pragma unroll
        for (int i = 0; i < 44; ++i) rr[i] = xs[kh][i];
#pragma unroll
        for (int kw = 0; kw < 5; ++kw) {
            float wv = wr[kh * 5 + kw];
#pragma unroll
            for (int w = 0; w < 40; ++w) conv[w] += rr[w + kw] * wv;
        }
    }
    float* op = out1 + (((size_t)(b * TT + h) * CC) + c) * 8;
#pragma unroll
    for (int j = 0; j < 8; ++j) {
        float m = 0.f;
#pragma unroll
        for (int p = 0; p < 5; ++p) m = fmaxf(m, conv[j * 5 + p] * sc + sh);
        op[j] = m;
    }
}

// ---------------- conv block 2: fp16 MFMA implicit GEMM (proven in R4) ----------------
__global__ __launch_bounds__(256) void conv2_mfma_kernel(
    const float* __restrict__ in, const f16* __restrict__ w2p,
    const float* __restrict__ b2, const float* __restrict__ g2,
    const float* __restrict__ bt2, const float* __restrict__ m2,
    const float* __restrict__ v2, float* __restrict__ out2) {
    int htile = blockIdx.x;                 // 64
    int b = blockIdx.y;                     // 16
    int h0 = htile * 8;
    int t = threadIdx.x;
    int lane = t & 63, wid = t >> 6;
    int m16 = lane & 15, kq = lane >> 4;

    __shared__ f16 lds_a[12 * 12 * 136];    // 39168 B

#pragma unroll
    for (int i = 0; i < 39; ++i) {
        int idx = t + i * 256;
        if (idx < 9792) ((unsigned*)lds_a)[idx] = 0u;
    }
    __syncthreads();

    f32x4 acc[4][4];
#pragma unroll
    for (int mf = 0; mf < 4; ++mf)
#pragma unroll
        for (int nf = 0; nf < 4; ++nf) acc[mf][nf] = (f32x4)(0.f);

    for (int cs = 0; cs < 2; ++cs) {
        if (cs) __syncthreads();
#pragma unroll
        for (int i = 0; i < 2; ++i) {
            int qq = t + i * 256;
            if (qq < 384) {
                int row = qq >> 5, ciq = qq & 31;
                int hp = h0 - 2 + row;
                float fv[32];
                if (hp >= 0 && hp < TT) {
                    const float4* src = (const float4*)(in + (((size_t)(b * TT + hp) * CC) + cs * 128 + ciq * 4) * 8);
#pragma unroll
                    for (int cc = 0; cc < 4; ++cc) {
                        float4 u0 = src[cc * 2], u1 = src[cc * 2 + 1];
                        fv[cc * 8 + 0] = u0.x; fv[cc * 8 + 1] = u0.y; fv[cc * 8 + 2] = u0.z; fv[cc * 8 + 3] = u0.w;
                        fv[cc * 8 + 4] = u1.x; fv[cc * 8 + 5] = u1.y; fv[cc * 8 + 6] = u1.z; fv[cc * 8 + 7] = u1.w;
                    }
                } else {
#pragma unroll
                    for (int z = 0; z < 32; ++z) fv[z] = 0.f;
                }
#pragma unroll
                for (int w = 0; w < 8; ++w) {
                    f16x4 hv = { (f16)fv[0 * 8 + w], (f16)fv[1 * 8 + w], (f16)fv[2 * 8 + w], (f16)fv[3 * 8 + w] };
                    *(f16x4*)&lds_a[row * 1632 + (w + 2) * 136 + ciq * 4] = hv;
                }
            }
        }
        __syncthreads();
        for (int kh = 0; kh < 5; ++kh) {
#pragma unroll
            for (int kw = 0; kw < 5; ++kw) {
                int tap = kh * 5 + kw;
#pragma unroll
                for (int cs4 = 0; cs4 < 4; ++cs4) {
                    f16x8 af[4];
#pragma unroll
                    for (int mf = 0; mf < 4; ++mf) {
                        int m = mf * 16 + m16;
                        int row = (m >> 3) + kh;
                        int wp = (m & 7) + kw;
                        af[mf] = *(const f16x8*)&lds_a[row * 1632 + wp * 136 + cs4 * 32 + kq * 8];
                    }
                    const f16x8* bp = (const f16x8*)w2p
                        + ((size_t)(((tap * 2 + cs) * 4 + cs4) * 16 + wid * 4) * 64 + lane);
#pragma unroll
                    for (int nf = 0; nf < 4; ++nf) {
                        f16x8 bf = bp[nf * 64];
#pragma unroll
                        for (int mf = 0; mf < 4; ++mf)
                            acc[mf][nf] = __builtin_amdgcn_mfma_f32_16x16x32_f16(af[mf], bf, acc[mf][nf], 0, 0, 0);
                    }
                }
            }
        }
    }

#pragma unroll
    for (int nf = 0; nf < 4; ++nf) {
        int co = wid * 64 + nf * 16 + m16;
        float sc = g2[co] * rsqrtf(v2[co] + 1e-5f);
        float sh = (b2[co] - m2[co]) * sc + bt2[co];
#pragma unroll
        for (int mf = 0; mf < 4; ++mf) {
            f32x4 v = acc[mf][nf];
            float p = 0.f;
            p = fmaxf(p, v[0] * sc + sh);
            p = fmaxf(p, v[1] * sc + sh);
            p = fmaxf(p, v[2] * sc + sh);
            p = fmaxf(p, v[3] * sc + sh);
            int dh = mf * 2 + (kq >> 1);
            int wout = kq & 1;
            out2[(((size_t)(b * TT + h0 + dh) * CC) + co) * 2 + wout] = p;
        }
    }
}

// ---------------- conv block 3: fp16 MFMA implicit GEMM ----------------
// Block: (htile of 16 h, b). M=32 (16h x 2w), N=256 co (4 waves), K = 15 taps x 256 ci.
// A[m][k]: m = dh*2+w, element = in[b][h0+dh+kh-2][ci][w+kw-2], kw in {1,2,3}.
// lds_a[row 20][wp 6][ci 136]; valid data at wp=2,3 (w'=0,1), rest zero.
__global__ __launch_bounds__(256) void conv3_mfma_kernel(
    const float* __restrict__ in, const f16* __restrict__ w3p,
    const float* __restrict__ b3, const float* __restrict__ g3,
    const float* __restrict__ bt3, const float* __restrict__ m3,
    const float* __restrict__ v3, float* __restrict__ out3) {
    int htile = blockIdx.x;                 // 32
    int b = blockIdx.y;                     // 16
    int h0 = htile * 16;
    int t = threadIdx.x;
    int lane = t & 63, wid = t >> 6;
    int m16 = lane & 15, quad = lane >> 4;
    int rb = m16 >> 1, wv = m16 & 1;        // dh-part, w

    __shared__ f16 lds_a[20 * 6 * 136];     // 32640 B

    for (int i = t; i < 8160; i += 256) ((unsigned*)lds_a)[i] = 0u;
    __syncthreads();

    f32x4 acc[2][4];
#pragma unroll
    for (int mf = 0; mf < 2; ++mf)
#pragma unroll
        for (int nf = 0; nf < 4; ++nf) acc[mf][nf] = (f32x4)(0.f);

    for (int cs = 0; cs < 2; ++cs) {
        if (cs) __syncthreads();
        // stage: 20 rows x 32 ci-quads; each task loads 4 ci x 2 w fp32 -> 2 f16x4 stores
#pragma unroll
        for (int i = 0; i < 3; ++i) {
            int qq = t + i * 256;
            if (qq < 640) {
                int row = qq >> 5, ciq = qq & 31;
                int hp = h0 - 2 + row;
                if (hp >= 0 && hp < TT) {
                    const float4* src = (const float4*)(in + (((size_t)(b * TT + hp) * CC) + cs * 128 + ciq * 4) * 2);
                    float4 u0 = src[0], u1 = src[1];   // (ci0,w0)(ci0,w1)(ci1,w0)(ci1,w1) | (ci2..)(ci3..)
                    f16x4 h0v = { (f16)u0.x, (f16)u0.z, (f16)u1.x, (f16)u1.z };   // w=0
                    f16x4 h1v = { (f16)u0.y, (f16)u0.w, (f16)u1.y, (f16)u1.w };   // w=1
                    *(f16x4*)&lds_a[row * 816 + 2 * 136 + ciq * 4] = h0v;
                    *(f16x4*)&lds_a[row * 816 + 3 * 136 + ciq * 4] = h1v;
                }
            }
        }
        __syncthreads();
        for (int kh = 0; kh < 5; ++kh) {
#pragma unroll
            for (int kw3 = 0; kw3 < 3; ++kw3) {     // kw = kw3+1
                int tap = kh * 3 + kw3;
#pragma unroll
                for (int cs4 = 0; cs4 < 4; ++cs4) {
                    f16x8 af[2];
#pragma unroll
                    for (int mf = 0; mf < 2; ++mf) {
                        int row = mf * 8 + rb + kh;
                        int wp = wv + kw3 + 1;
                        af[mf] = *(const f16x8*)&lds_a[row * 816 + wp * 136 + cs4 * 32 + quad * 8];
                    }
                    const f16x8* bp = (const f16x8*)w3p
                        + ((size_t)(((tap * 2 + cs) * 4 + cs4) * 16 + wid * 4) * 64 + lane);
#pragma unroll
                    for (int nf = 0; nf < 4; ++nf) {
                        f16x8 bf = bp[nf * 64];
#pragma unroll
                        for (int mf = 0; mf < 2; ++mf)
                            acc[mf][nf] = __builtin_amdgcn_mfma_f32_16x16x32_f16(af[mf], bf, acc[mf][nf], 0, 0, 0);
                    }
                }
            }
        }
    }

    // epilogue: BN + ReLU + pool2(w). D rows: m = mf*16 + quad*4 + reg ->
    // regs (0,1) = (dh = mf*8+quad*2, w=0/1); regs (2,3) = dh+1.
#pragma unroll
    for (int nf = 0; nf < 4; ++nf) {
        int co = wid * 64 + nf * 16 + m16;
        float sc = g3[co] * rsqrtf(v3[co] + 1e-5f);
        float sh = (b3[co] - m3[co]) * sc + bt3[co];
#pragma unroll
        for (int mf = 0; mf < 2; ++mf) {
            f32x4 v = acc[mf][nf];
            float p0 = fmaxf(0.f, fmaxf(v[0], v[1]) * sc + sh);
            p0 = fmaxf(p0, fmaxf(0.f, fminf(v[0], v[1]) * sc + sh));   // robust if sc<0
            float p1 = fmaxf(0.f, fmaxf(v[2], v[3]) * sc + sh);
            p1 = fmaxf(p1, fmaxf(0.f, fminf(v[2], v[3]) * sc + sh));
            int h = h0 + mf * 8 + quad * 2;
            out3[((size_t)(b * TT + h) * CC) + co] = p0;
            out3[((size_t)(b * TT + h + 1) * CC) + co] = p1;
        }
    }
}

// ---------------- gi_all GEMM (fp32, unchanged) ----------------
__global__ __launch_bounds__(256) void gi_kernel(
    const float* __restrict__ feats, const float* __restrict__ wiht,
    const float* __restrict__ bih, float* __restrict__ gi) {
    int bt0 = blockIdx.x * 16;
    int g = blockIdx.y * 256 + threadIdx.x;
    float acc[16];
    float bv = bih[g];
#pragma unroll
    for (int i = 0; i < 16; ++i) acc[i] = bv;
    for (int c = 0; c < CC; ++c) {
        float wv = wiht[c * GG + g];
#pragma unroll
        for (int i = 0; i < 16; ++i) acc[i] += feats[(size_t)(bt0 + i) * CC + c] * wv;
    }
#pragma unroll
    for (int i = 0; i < 16; ++i) {
        int bt = bt0 + i;
        int b = bt >> 9, s = bt & 511;
        gi[((size_t)s * 16 + b) * GG + g] = acc[i];
    }
}

// ---------------- GRU scan: ONE block, MFMA over batch dim ----------------
// 1024 threads = 16 waves on one CU. Gate GEMM per step: [16b x 256k] @ [256k x 768g].
// Wave w owns gate tiles {w, w+16, w+32} == complete (r,z,n) triplet for h cols
// w*16..w*16+15 -> gates never leave registers. Master h is fp32 in per-lane regs
// (hold[4]); fp16 A-copy of h in LDS (8 KB) feeds MFMA. B (whhp) streams from L2,
// 393 KB/step, L2-resident across all 512 steps. Classifier = 8 extra MFMAs on wave 0.
__global__ __launch_bounds__(1024) void gru_mfma_kernel(
    const float* __restrict__ gi, const f16* __restrict__ whhp,
    const float* __restrict__ bhh, const f16* __restrict__ wclsp,
    const float* __restrict__ bcls, float* __restrict__ out) {
    int t = threadIdx.x;
    int w = t >> 6, lane = t & 63;
    int n16 = lane & 15, quad = lane >> 4;
    int c = w * 16 + n16;                 // this lane's h/gate column
    __shared__ f16 hA[16 * 264];          // [b][k] fp16 A-copy, pad 8 halves

    for (int i = t; i < 16 * 264; i += 1024) hA[i] = (f16)0.f;
    float bh0 = bhh[c], bh1 = bhh[HH + c], bh2 = bhh[2 * HH + c];
    float bclsv = bcls[n16];
    float hold[4] = {0.f, 0.f, 0.f, 0.f};
    __syncthreads();

    for (int s = 0; s < TT; ++s) {
        f32x4 ar = (f32x4)(0.f), az = (f32x4)(0.f), an = (f32x4)(0.f);
#pragma unroll
        for (int kf = 0; kf < 8; ++kf) {
            f16x8 af = *(const f16x8*)&hA[n16 * 264 + kf * 32 + quad * 8];
            const f16x8* bp = (const f16x8*)whhp + (size_t)kf * 3072 + lane;
            f16x8 b0 = bp[(size_t)w * 64];
            f16x8 b1 = bp[(size_t)(w + 16) * 64];
            f16x8 b2 = bp[(size_t)(w + 32) * 64];
            ar = __builtin_amdgcn_mfma_f32_16x16x32_f16(af, b0, ar, 0, 0, 0);
            az = __builtin_amdgcn_mfma_f32_16x16x32_f16(af, b1, az, 0, 0, 0);
            an = __builtin_amdgcn_mfma_f32_16x16x32_f16(af, b2, an, 0, 0, 0);
        }
        const float* gp = gi + (size_t)s * (BB * GG);
        float hn[4];
#pragma unroll
        for (int r = 0; r < 4; ++r) {
            int b = quad * 4 + r;
            const float* gb = gp + b * GG;
            float rr = 1.f / (1.f + expf(-(gb[c] + bh0 + ar[r])));
            float zz = 1.f / (1.f + expf(-(gb[HH + c] + bh1 + az[r])));
            float nn = tanhf(gb[2 * HH + c] + rr * (bh2 + an[r]));
            hn[r] = (1.f - zz) * nn + zz * hold[r];
            hold[r] = hn[r];
        }
        __syncthreads();                  // B1: all hA reads of step s complete
#pragma unroll
        for (int r = 0; r < 4; ++r)
            hA[(quad * 4 + r) * 264 + c] = (f16)hn[r];
        __syncthreads();                  // B2: updated h visible

        if (w == 0) {                     // classifier: [16b x 256c] @ [256c x 16nb]
            f32x4 ac = (f32x4)(0.f);
#pragma unroll
            for (int kf = 0; kf < 8; ++kf) {
                f16x8 af = *(const f16x8*)&hA[n16 * 264 + kf * 32 + quad * 8];
                f16x8 bf = ((const f16x8*)wclsp)[kf * 64 + lane];
                ac = __builtin_amdgcn_mfma_f32_16x16x32_f16(af, bf, ac, 0, 0, 0);
            }
#pragma unroll
            for (int r = 0; r < 4; ++r) {
                int b = quad * 4 + r;
                out[((size_t)b * TT + s) * NB + n16] = ac[r] + bclsv;
            }
        }
    }
}

extern "C" void kernel_launch(void* const* d_in, const int* in_sizes, int n_in,
                              void* d_out, int out_size, void* d_ws, size_t ws_size,
                              hipStream_t stream) {
    const float* x    = (const float*)d_in[0];
    const float* w1   = (const float*)d_in[1];
    const float* b1   = (const float*)d_in[2];
    const float* g1   = (const float*)d_in[3];
    const float* bt1  = (const float*)d_in[4];
    const float* m1   = (const float*)d_in[5];
    const float* v1   = (const float*)d_in[6];
    const float* w2   = (const float*)d_in[7];
    const float* b2   = (const float*)d_in[8];
    const float* g2   = (const float*)d_in[9];
    const float* bt2  = (const float*)d_in[10];
    const float* m2   = (const float*)d_in[11];
    const float* v2   = (const float*)d_in[12];
    const float* w3   = (const float*)d_in[13];
    const float* b3   = (const float*)d_in[14];
    const float* g3   = (const float*)d_in[15];
    const float* bt3  = (const float*)d_in[16];
    const float* m3   = (const float*)d_in[17];
    const float* v3   = (const float*)d_in[18];
    const float* wih  = (const float*)d_in[19];
    const float* whh  = (const float*)d_in[20];
    const float* bih  = (const float*)d_in[21];
    const float* bhh  = (const float*)d_in[22];
    const float* wcls = (const float*)d_in[23];
    const float* bcls = (const float*)d_in[24];

    float* ws   = (float*)d_ws;
    float* out1 = ws + O_OUT1;
    float* out2 = ws + O_OUT2;
    float* out3 = ws + O_OUT3;
    float* gi   = ws + O_GI;               // aliases out1 (dead after conv2)
    f16*   w2p  = (f16*)(ws + O_W2P);
    f16*   w3p  = (f16*)(ws + O_W3P);
    f16*   wclsp = (f16*)(ws + O_W3P) + 983040;
    float* wiht = ws + O_WIHT;
    f16*   whhp = (f16*)(ws + O_WHHP);     // aliases out2 (dead after conv3)
    float* fout = (float*)d_out;

    // weight prep
    pack_w2_kernel<<<800, 256, 0, stream>>>(w2, w2p);
    pack_w3_kernel<<<480, 256, 0, stream>>>(w3, w3p);
    pack_wcls_kernel<<<1, 512, 0, stream>>>(wcls, wclsp);
    transpose_wih_kernel<<<768, 256, 0, stream>>>(wih, wiht);

    // conv stack
    conv1_kernel<<<dim3(512, 16), 256, 0, stream>>>(x, w1, b1, g1, bt1, m1, v1, out1);
    conv2_mfma_kernel<<<dim3(64, 16), 256, 0, stream>>>(out1, w2p, b2, g2, bt2, m2, v2, out2);
    conv3_mfma_kernel<<<dim3(32, 16), 256, 0, stream>>>(out2, w3p, b3, g3, bt3, m3, v3, out3);

    // whh fragment-pack into the (now dead) out2 region
    pack_whh_kernel<<<96, 256, 0, stream>>>(whh, whhp);

    // input-to-hidden GEMM (writes over out1 region; conv2 already consumed it)
    gi_kernel<<<dim3(512, 3), 256, 0, stream>>>(out3, wiht, bih, gi);

    // GRU scan: one block, one CU, zero communication
    gru_mfma_kernel<<<1, 1024, 0, stream>>>(gi, whhp, bhh, wclsp, bcls, fout);
}

// Round 6
// 4285.286 us; speedup vs baseline: 3.1262x; 1.0137x over previous
//
#include <hip/hip_runtime.h>
#include <hip/hip_bf16.h>
#include <math.h>

// Problem constants
#define BB 16
#define TT 512
#define FF 40
#define CC 256
#define HH 256
#define GG 768   // 3*H
#define NB 16

typedef _Float16 f16;
typedef __attribute__((ext_vector_type(8))) _Float16 f16x8;
typedef __attribute__((ext_vector_type(4))) _Float16 f16x4;
typedef __attribute__((ext_vector_type(4))) float f32x4;

// Workspace layout (float offsets).
// gi aliases out1 (out1 dead after conv2); whhp aliases out2 (packed after conv3).
#define O_OUT1 0u                       // [b][h][c][8]  16777216
#define O_GI   0u                       // [s][b][768]   6291456 (aliases out1)
#define O_OUT2 16777216u                // [b][h][c][2]  4194304
#define O_WHHP O_OUT2                   // 196608 halves (aliases dead out2)
#define O_OUT3 20971520u                // [b][h][c]     2097152  (== feats[b][t][c])
#define O_W2P  23068672u                // packed fp16 conv2 weights, 1638400 halves
#define O_W3P  24707072u                // packed fp16 conv3 weights, 983040 halves (+ wclsp 4096 halves)
#define O_WIHT 26345472u                // [c][g] 196608
// total 26542080 floats = 106.2 MB (unchanged footprint)

// ---------------- weight prep ----------------
__global__ void transpose_wih_kernel(const float* __restrict__ wih, float* __restrict__ wiht) {
    int g = blockIdx.x;          // 768
    int c = threadIdx.x;         // 256
    wiht[c * 768 + g] = wih[g * 256 + c];
}

// conv2 weights -> MFMA B-fragment order (fp16). Layout verified on HW (R4/R5).
__global__ __launch_bounds__(256) void pack_w2_kernel(const float* __restrict__ w2, f16* __restrict__ w2p) {
    int e = blockIdx.x * 256 + threadIdx.x;     // grid 800 -> 204800 entries
    int lane = e & 63;
    int r1 = e >> 6;
    int ntile = r1 & 15;
    int r2 = r1 >> 4;
    int cs4 = r2 & 3;
    int r3 = r2 >> 2;
    int cs = r3 & 1;
    int tap = r3 >> 1;                          // 0..24
    int co = ntile * 16 + (lane & 15);
    int ci0 = cs * 128 + cs4 * 32 + (lane >> 4) * 8;
    f16x8 v;
#pragma unroll
    for (int j = 0; j < 8; ++j)
        v[j] = (f16)w2[(size_t)co * 6400 + (ci0 + j) * 25 + tap];
    *(f16x8*)(w2p + (size_t)e * 8) = v;
}

// conv3 weights: only kw in {1,2,3} touch the W=2 input -> 15 taps.
__global__ __launch_bounds__(256) void pack_w3_kernel(const float* __restrict__ w3, f16* __restrict__ w3p) {
    int e = blockIdx.x * 256 + threadIdx.x;     // grid 480 -> 122880 entries
    int lane = e & 63;
    int r1 = e >> 6;
    int ntile = r1 & 15;
    int r2 = r1 >> 4;
    int cs4 = r2 & 3;
    int r3 = r2 >> 2;
    int cs = r3 & 1;
    int tap = r3 >> 1;                          // 0..14
    int kh = tap / 3, kw = tap % 3 + 1;
    int co = ntile * 16 + (lane & 15);
    int ci0 = cs * 128 + cs4 * 32 + (lane >> 4) * 8;
    f16x8 v;
#pragma unroll
    for (int j = 0; j < 8; ++j)
        v[j] = (f16)w3[(size_t)co * 6400 + (ci0 + j) * 25 + kh * 5 + kw];
    *(f16x8*)(w3p + (size_t)e * 8) = v;
}

// w_hh -> B-fragment order: entry e = (kf*48 + tile)*64 + lane.
// B[k][g]: g = tile*16 + (lane&15), k = kf*32 + (lane>>4)*8 + j.
__global__ __launch_bounds__(256) void pack_whh_kernel(const float* __restrict__ whh, f16* __restrict__ whhp) {
    int e = blockIdx.x * 256 + threadIdx.x;     // grid 96 -> 24576 entries
    int lane = e & 63;
    int r1 = e >> 6;                            // 0..383
    int tile = r1 % 48, kf = r1 / 48;
    int g = tile * 16 + (lane & 15);
    int k0 = kf * 32 + (lane >> 4) * 8;
    f16x8 v;
#pragma unroll
    for (int j = 0; j < 8; ++j)
        v[j] = (f16)whh[(size_t)g * HH + k0 + j];
    *(f16x8*)(whhp + (size_t)e * 8) = v;
}

// w_cls -> B-fragment order: entry e = kf*64 + lane; B[k=c][n=nb].
__global__ void pack_wcls_kernel(const float* __restrict__ wcls, f16* __restrict__ wclsp) {
    int e = threadIdx.x;                        // 512
    int lane = e & 63, kf = e >> 6;
    int nb = lane & 15;
    int c0 = kf * 32 + (lane >> 4) * 8;
    f16x8 v;
#pragma unroll
    for (int j = 0; j < 8; ++j)
        v[j] = (f16)wcls[nb * HH + c0 + j];
    *(f16x8*)(wclsp + (size_t)e * 8) = v;
}

// ---------------- conv block 1 (fp32, unchanged) ----------------
__global__ __launch_bounds__(256) void conv1_kernel(
    const float* __restrict__ x, const float* __restrict__ w1,
    const float* __restrict__ b1, const float* __restrict__ g1,
    const float* __restrict__ bt1, const float* __restrict__ m1,
    const float* __restrict__ v1, float* __restrict__ out1) {
    int h = blockIdx.x;          // 512
    int b = blockIdx.y;          // 16
    int c = threadIdx.x;         // 256
    __shared__ float xs[5][44];
    int t = threadIdx.x;
    if (t < 220) {
        int rr = t / 44, cc = t % 44;
        int hh = h + rr - 2, ww = cc - 2;
        float v = 0.f;
        if (hh >= 0 && hh < TT && ww >= 0 && ww < FF) v = x[(b * TT + hh) * FF + ww];
        xs[rr][cc] = v;
    }
    __syncthreads();
    float wr[25];
#pragma unroll
    for (int i = 0; i < 25; ++i) wr[i] = w1[c * 25 + i];
    float sc = g1[c] * rsqrtf(v1[c] + 1e-5f);
    float sh = (b1[c] - m1[c]) * sc + bt1[c];
    float conv[40];
#pragma unroll
    for (int w = 0; w < 40; ++w) conv[w] = 0.f;
#pragma unroll
    for (int kh = 0; kh < 5; ++kh) {
        float rr[44];
#pragma unroll
        for (int i = 0; i < 44; ++i) rr[i] = xs[kh][i];
#pragma unroll
        for (int kw = 0; kw < 5; ++kw) {
            float wv = wr[kh * 5 + kw];
#pragma unroll
            for (int w = 0; w < 40; ++w) conv[w] += rr[w + kw] * wv;
        }
    }
    float* op = out1 + (((size_t)(b * TT + h) * CC) + c) * 8;
#pragma unroll
    for (int j = 0; j < 8; ++j) {
        float m = 0.f;
#pragma unroll
        for (int p = 0; p < 5; ++p) m = fmaxf(m, conv[j * 5 + p] * sc + sh);
        op[j] = m;
    }
}

// ---------------- conv block 2: fp16 MFMA implicit GEMM (proven) ----------------
__global__ __launch_bounds__(256) void conv2_mfma_kernel(
    const float* __restrict__ in, const f16* __restrict__ w2p,
    const float* __restrict__ b2, const float* __restrict__ g2,
    const float* __restrict__ bt2, const float* __restrict__ m2,
    const float* __restrict__ v2, float* __restrict__ out2) {
    int htile = blockIdx.x;                 // 64
    int b = blockIdx.y;                     // 16
    int h0 = htile * 8;
    int t = threadIdx.x;
    int lane = t & 63, wid = t >> 6;
    int m16 = lane & 15, kq = lane >> 4;

    __shared__ f16 lds_a[12 * 12 * 136];    // 39168 B

#pragma unroll
    for (int i = 0; i < 39; ++i) {
        int idx = t + i * 256;
        if (idx < 9792) ((unsigned*)lds_a)[idx] = 0u;
    }
    __syncthreads();

    f32x4 acc[4][4];
#pragma unroll
    for (int mf = 0; mf < 4; ++mf)
#pragma unroll
        for (int nf = 0; nf < 4; ++nf) acc[mf][nf] = (f32x4)(0.f);

    for (int cs = 0; cs < 2; ++cs) {
        if (cs) __syncthreads();
#pragma unroll
        for (int i = 0; i < 2; ++i) {
            int qq = t + i * 256;
            if (qq < 384) {
                int row = qq >> 5, ciq = qq & 31;
                int hp = h0 - 2 + row;
                float fv[32];
                if (hp >= 0 && hp < TT) {
                    const float4* src = (const float4*)(in + (((size_t)(b * TT + hp) * CC) + cs * 128 + ciq * 4) * 8);
#pragma unroll
                    for (int cc = 0; cc < 4; ++cc) {
                        float4 u0 = src[cc * 2], u1 = src[cc * 2 + 1];
                        fv[cc * 8 + 0] = u0.x; fv[cc * 8 + 1] = u0.y; fv[cc * 8 + 2] = u0.z; fv[cc * 8 + 3] = u0.w;
                        fv[cc * 8 + 4] = u1.x; fv[cc * 8 + 5] = u1.y; fv[cc * 8 + 6] = u1.z; fv[cc * 8 + 7] = u1.w;
                    }
                } else {
#pragma unroll
                    for (int z = 0; z < 32; ++z) fv[z] = 0.f;
                }
#pragma unroll
                for (int w = 0; w < 8; ++w) {
                    f16x4 hv = { (f16)fv[0 * 8 + w], (f16)fv[1 * 8 + w], (f16)fv[2 * 8 + w], (f16)fv[3 * 8 + w] };
                    *(f16x4*)&lds_a[row * 1632 + (w + 2) * 136 + ciq * 4] = hv;
                }
            }
        }
        __syncthreads();
        for (int kh = 0; kh < 5; ++kh) {
#pragma unroll
            for (int kw = 0; kw < 5; ++kw) {
                int tap = kh * 5 + kw;
#pragma unroll
                for (int cs4 = 0; cs4 < 4; ++cs4) {
                    f16x8 af[4];
#pragma unroll
                    for (int mf = 0; mf < 4; ++mf) {
                        int m = mf * 16 + m16;
                        int row = (m >> 3) + kh;
                        int wp = (m & 7) + kw;
                        af[mf] = *(const f16x8*)&lds_a[row * 1632 + wp * 136 + cs4 * 32 + kq * 8];
                    }
                    const f16x8* bp = (const f16x8*)w2p
                        + ((size_t)(((tap * 2 + cs) * 4 + cs4) * 16 + wid * 4) * 64 + lane);
#pragma unroll
                    for (int nf = 0; nf < 4; ++nf) {
                        f16x8 bf = bp[nf * 64];
#pragma unroll
                        for (int mf = 0; mf < 4; ++mf)
                            acc[mf][nf] = __builtin_amdgcn_mfma_f32_16x16x32_f16(af[mf], bf, acc[mf][nf], 0, 0, 0);
                    }
                }
            }
        }
    }

#pragma unroll
    for (int nf = 0; nf < 4; ++nf) {
        int co = wid * 64 + nf * 16 + m16;
        float sc = g2[co] * rsqrtf(v2[co] + 1e-5f);
        float sh = (b2[co] - m2[co]) * sc + bt2[co];
#pragma unroll
        for (int mf = 0; mf < 4; ++mf) {
            f32x4 v = acc[mf][nf];
            float p = 0.f;
            p = fmaxf(p, v[0] * sc + sh);
            p = fmaxf(p, v[1] * sc + sh);
            p = fmaxf(p, v[2] * sc + sh);
            p = fmaxf(p, v[3] * sc + sh);
            int dh = mf * 2 + (kq >> 1);
            int wout = kq & 1;
            out2[(((size_t)(b * TT + h0 + dh) * CC) + co) * 2 + wout] = p;
        }
    }
}

// ---------------- conv block 3: fp16 MFMA implicit GEMM (proven) ----------------
__global__ __launch_bounds__(256) void conv3_mfma_kernel(
    const float* __restrict__ in, const f16* __restrict__ w3p,
    const float* __restrict__ b3, const float* __restrict__ g3,
    const float* __restrict__ bt3, const float* __restrict__ m3,
    const float* __restrict__ v3, float* __restrict__ out3) {
    int htile = blockIdx.x;                 // 32
    int b = blockIdx.y;                     // 16
    int h0 = htile * 16;
    int t = threadIdx.x;
    int lane = t & 63, wid = t >> 6;
    int m16 = lane & 15, quad = lane >> 4;
    int rb = m16 >> 1, wv = m16 & 1;

    __shared__ f16 lds_a[20 * 6 * 136];     // 32640 B

    for (int i = t; i < 8160; i += 256) ((unsigned*)lds_a)[i] = 0u;
    __syncthreads();

    f32x4 acc[2][4];
#pragma unroll
    for (int mf = 0; mf < 2; ++mf)
#pragma unroll
        for (int nf = 0; nf < 4; ++nf) acc[mf][nf] = (f32x4)(0.f);

    for (int cs = 0; cs < 2; ++cs) {
        if (cs) __syncthreads();
#pragma unroll
        for (int i = 0; i < 3; ++i) {
            int qq = t + i * 256;
            if (qq < 640) {
                int row = qq >> 5, ciq = qq & 31;
                int hp = h0 - 2 + row;
                if (hp >= 0 && hp < TT) {
                    const float4* src = (const float4*)(in + (((size_t)(b * TT + hp) * CC) + cs * 128 + ciq * 4) * 2);
                    float4 u0 = src[0], u1 = src[1];
                    f16x4 h0v = { (f16)u0.x, (f16)u0.z, (f16)u1.x, (f16)u1.z };
                    f16x4 h1v = { (f16)u0.y, (f16)u0.w, (f16)u1.y, (f16)u1.w };
                    *(f16x4*)&lds_a[row * 816 + 2 * 136 + ciq * 4] = h0v;
                    *(f16x4*)&lds_a[row * 816 + 3 * 136 + ciq * 4] = h1v;
                }
            }
        }
        __syncthreads();
        for (int kh = 0; kh < 5; ++kh) {
#pragma unroll
            for (int kw3 = 0; kw3 < 3; ++kw3) {
                int tap = kh * 3 + kw3;
#pragma unroll
                for (int cs4 = 0; cs4 < 4; ++cs4) {
                    f16x8 af[2];
#pragma unroll
                    for (int mf = 0; mf < 2; ++mf) {
                        int row = mf * 8 + rb + kh;
                        int wp = wv + kw3 + 1;
                        af[mf] = *(const f16x8*)&lds_a[row * 816 + wp * 136 + cs4 * 32 + quad * 8];
                    }
                    const f16x8* bp = (const f16x8*)w3p
                        + ((size_t)(((tap * 2 + cs) * 4 + cs4) * 16 + wid * 4) * 64 + lane);
#pragma unroll
                    for (int nf = 0; nf < 4; ++nf) {
                        f16x8 bf = bp[nf * 64];
#pragma unroll
                        for (int mf = 0; mf < 2; ++mf)
                            acc[mf][nf] = __builtin_amdgcn_mfma_f32_16x16x32_f16(af[mf], bf, acc[mf][nf], 0, 0, 0);
                    }
                }
            }
        }
    }

#pragma unroll
    for (int nf = 0; nf < 4; ++nf) {
        int co = wid * 64 + nf * 16 + m16;
        float sc = g3[co] * rsqrtf(v3[co] + 1e-5f);
        float sh = (b3[co] - m3[co]) * sc + bt3[co];
#pragma unroll
        for (int mf = 0; mf < 2; ++mf) {
            f32x4 v = acc[mf][nf];
            float p0 = fmaxf(0.f, fmaxf(v[0], v[1]) * sc + sh);
            p0 = fmaxf(p0, fmaxf(0.f, fminf(v[0], v[1]) * sc + sh));
            float p1 = fmaxf(0.f, fmaxf(v[2], v[3]) * sc + sh);
            p1 = fmaxf(p1, fmaxf(0.f, fminf(v[2], v[3]) * sc + sh));
            int h = h0 + mf * 8 + quad * 2;
            out3[((size_t)(b * TT + h) * CC) + co] = p0;
            out3[((size_t)(b * TT + h + 1) * CC) + co] = p1;
        }
    }
}

// ---------------- gi_all GEMM (fp32, unchanged) ----------------
__global__ __launch_bounds__(256) void gi_kernel(
    const float* __restrict__ feats, const float* __restrict__ wiht,
    const float* __restrict__ bih, float* __restrict__ gi) {
    int bt0 = blockIdx.x * 16;
    int g = blockIdx.y * 256 + threadIdx.x;
    float acc[16];
    float bv = bih[g];
#pragma unroll
    for (int i = 0; i < 16; ++i) acc[i] = bv;
    for (int c = 0; c < CC; ++c) {
        float wv = wiht[c * GG + g];
#pragma unroll
        for (int i = 0; i < 16; ++i) acc[i] += feats[(size_t)(bt0 + i) * CC + c] * wv;
    }
#pragma unroll
    for (int i = 0; i < 16; ++i) {
        int bt = bt0 + i;
        int b = bt >> 9, s = bt & 511;
        gi[((size_t)s * 16 + b) * GG + g] = acc[i];
    }
}

// ---------------- GRU scan: ONE block, ALL w_hh weights in registers ----------------
// 512 threads = 8 waves, 2 waves/SIMD -> 256-VGPR budget. Wave w owns gate columns
// w*32..w*32+31 as two 16-col groups with their full (r,z,n) triplets: 6 B-tiles =
// 192 VGPRs of fp16 fragments, preloaded ONCE. Per step: zero weight traffic; only
// gi reads (48 KB) + 8.4 KB hA LDS round-trip. Master h fp32 in registers.
__global__ __launch_bounds__(512, 2) void gru_mfma_kernel(
    const float* __restrict__ gi, const f16* __restrict__ whhp,
    const float* __restrict__ bhh, const f16* __restrict__ wclsp,
    const float* __restrict__ bcls, float* __restrict__ out) {
    int t = threadIdx.x;
    int w = t >> 6, lane = t & 63;        // w = 0..7
    int n16 = lane & 15, quad = lane >> 4;
    __shared__ f16 hA[16 * 264];          // [b][k] fp16 A-copy, pad 8 halves

    for (int i = t; i < 16 * 264; i += 512) hA[i] = (f16)0.f;

    // preload 6 weight tiles: gate g (0=r,1=z,2=n), col-group p -> tile g*16 + w*2 + p
    f16x8 wfrag[8][6];
#pragma unroll
    for (int kf = 0; kf < 8; ++kf)
#pragma unroll
        for (int g = 0; g < 3; ++g)
#pragma unroll
            for (int p = 0; p < 2; ++p)
                wfrag[kf][g * 2 + p] =
                    ((const f16x8*)whhp)[(size_t)(kf * 48 + g * 16 + w * 2 + p) * 64 + lane];

    int c0 = w * 32 + n16, c1 = c0 + 16;
    float bh[3][2];
#pragma unroll
    for (int g = 0; g < 3; ++g) { bh[g][0] = bhh[g * HH + c0]; bh[g][1] = bhh[g * HH + c1]; }
    float bclsv = bcls[n16];
    float hold[2][4] = {{0.f, 0.f, 0.f, 0.f}, {0.f, 0.f, 0.f, 0.f}};
    __syncthreads();

    for (int s = 0; s < TT; ++s) {
        f32x4 acc[3][2];
#pragma unroll
        for (int g = 0; g < 3; ++g) { acc[g][0] = (f32x4)(0.f); acc[g][1] = (f32x4)(0.f); }
#pragma unroll
        for (int kf = 0; kf < 8; ++kf) {
            f16x8 af = *(const f16x8*)&hA[n16 * 264 + kf * 32 + quad * 8];
#pragma unroll
            for (int g = 0; g < 3; ++g)
#pragma unroll
                for (int p = 0; p < 2; ++p)
                    acc[g][p] = __builtin_amdgcn_mfma_f32_16x16x32_f16(af, wfrag[kf][g * 2 + p], acc[g][p], 0, 0, 0);
        }
        const float* gp = gi + (size_t)s * (BB * GG);
#pragma unroll
        for (int r = 0; r < 4; ++r) {
            int b = quad * 4 + r;
            const float* gb = gp + b * GG;
#pragma unroll
            for (int p = 0; p < 2; ++p) {
                int c = p ? c1 : c0;
                float rr = 1.f / (1.f + expf(-(gb[c] + bh[0][p] + acc[0][p][r])));
                float zz = 1.f / (1.f + expf(-(gb[HH + c] + bh[1][p] + acc[1][p][r])));
                float nn = tanhf(gb[2 * HH + c] + rr * (bh[2][p] + acc[2][p][r]));
                hold[p][r] = (1.f - zz) * nn + zz * hold[p][r];
            }
        }
        __syncthreads();                  // B1: all hA reads of step s complete
#pragma unroll
        for (int r = 0; r < 4; ++r) {
            int b = quad * 4 + r;
            hA[b * 264 + c0] = (f16)hold[0][r];
            hA[b * 264 + c1] = (f16)hold[1][r];
        }
        __syncthreads();                  // B2: updated h visible

        if (w == 0) {                     // classifier: [16b x 256c] @ [256c x 16nb]
            f32x4 ac = (f32x4)(0.f);
#pragma unroll
            for (int kf = 0; kf < 8; ++kf) {
                f16x8 af = *(const f16x8*)&hA[n16 * 264 + kf * 32 + quad * 8];
                f16x8 bf = ((const f16x8*)wclsp)[kf * 64 + lane];
                ac = __builtin_amdgcn_mfma_f32_16x16x32_f16(af, bf, ac, 0, 0, 0);
            }
#pragma unroll
            for (int r = 0; r < 4; ++r)
                out[((size_t)(quad * 4 + r) * TT + s) * NB + n16] = ac[r] + bclsv;
        }
    }
}

extern "C" void kernel_launch(void* const* d_in, const int* in_sizes, int n_in,
                              void* d_out, int out_size, void* d_ws, size_t ws_size,
                              hipStream_t stream) {
    const float* x    = (const float*)d_in[0];
    const float* w1   = (const float*)d_in[1];
    const float* b1   = (const float*)d_in[2];
    const float* g1   = (const float*)d_in[3];
    const float* bt1  = (const float*)d_in[4];
    const float* m1   = (const float*)d_in[5];
    const float* v1   = (const float*)d_in[6];
    const float* w2   = (const float*)d_in[7];
    const float* b2   = (const float*)d_in[8];
    const float* g2   = (const float*)d_in[9];
    const float* bt2  = (const float*)d_in[10];
    const float* m2   = (const float*)d_in[11];
    const float* v2   = (const float*)d_in[12];
    const float* w3   = (const float*)d_in[13];
    const float* b3   = (const float*)d_in[14];
    const float* g3   = (const float*)d_in[15];
    const float* bt3  = (const float*)d_in[16];
    const float* m3   = (const float*)d_in[17];
    const float* v3   = (const float*)d_in[18];
    const float* wih  = (const float*)d_in[19];
    const float* whh  = (const float*)d_in[20];
    const float* bih  = (const float*)d_in[21];
    const float* bhh  = (const float*)d_in[22];
    const float* wcls = (const float*)d_in[23];
    const float* bcls = (const float*)d_in[24];

    float* ws   = (float*)d_ws;
    float* out1 = ws + O_OUT1;
    float* out2 = ws + O_OUT2;
    float* out3 = ws + O_OUT3;
    float* gi   = ws + O_GI;               // aliases out1 (dead after conv2)
    f16*   w2p  = (f16*)(ws + O_W2P);
    f16*   w3p  = (f16*)(ws + O_W3P);
    f16*   wclsp = (f16*)(ws + O_W3P) + 983040;
    float* wiht = ws + O_WIHT;
    f16*   whhp = (f16*)(ws + O_WHHP);     // aliases out2 (dead after conv3)
    float* fout = (float*)d_out;

    // weight prep
    pack_w2_kernel<<<800, 256, 0, stream>>>(w2, w2p);
    pack_w3_kernel<<<480, 256, 0, stream>>>(w3, w3p);
    pack_wcls_kernel<<<1, 512, 0, stream>>>(wcls, wclsp);
    transpose_wih_kernel<<<768, 256, 0, stream>>>(wih, wiht);

    // conv stack
    conv1_kernel<<<dim3(512, 16), 256, 0, stream>>>(x, w1, b1, g1, bt1, m1, v1, out1);
    conv2_mfma_kernel<<<dim3(64, 16), 256, 0, stream>>>(out1, w2p, b2, g2, bt2, m2, v2, out2);
    conv3_mfma_kernel<<<dim3(32, 16), 256, 0, stream>>>(out2, w3p, b3, g3, bt3, m3, v3, out3);

    // whh fragment-pack into the (now dead) out2 region
    pack_whh_kernel<<<96, 256, 0, stream>>>(whh, whhp);

    // input-to-hidden GEMM (writes over out1 region; conv2 already consumed it)
    gi_kernel<<<dim3(512, 3), 256, 0, stream>>>(out3, wiht, bih, gi);

    // GRU scan: one block, one CU, all weights register-resident
    gru_mfma_kernel<<<1, 512, 0, stream>>>(gi, whhp, bhh, wclsp, bcls, fout);
}

// Round 7
// 2058.405 us; speedup vs baseline: 6.5082x; 2.0818x over previous
//
#include <hip/hip_runtime.h>
#include <hip/hip_bf16.h>
#include <math.h>

// Problem constants
#define BB 16
#define TT 512
#define FF 40
#define CC 256
#define HH 256
#define GG 768   // 3*H
#define NB 16

typedef _Float16 f16;
typedef __attribute__((ext_vector_type(8))) _Float16 f16x8;
typedef __attribute__((ext_vector_type(4))) _Float16 f16x4;
typedef __attribute__((ext_vector_type(4))) float f32x4;

// Workspace layout (float offsets).
// gih aliases out1 (dead after conv2); whhp aliases out2 (dead after conv3);
// hsave aliases out3 (dead after gi_kernel).
#define O_OUT1 0u                       // [b][h][c][8]  16777216
#define O_GI   0u                       // gih [s][b][768] f16, 12 MB (aliases out1)
#define O_OUT2 16777216u                // [b][h][c][2]  4194304
#define O_WHHP O_OUT2                   // 196608 halves (aliases dead out2)
#define O_OUT3 20971520u                // [b][h][c] 2097152 (== feats); hsave f16 aliases after gi
#define O_W2P  23068672u                // packed fp16 conv2 weights, 1638400 halves
#define O_W3P  24707072u                // packed fp16 conv3 weights, 983040 halves (+ wclsp 4096 halves)
#define O_WIHT 26345472u                // [c][g] 196608
// total 26542080 floats = 106.2 MB

__device__ __forceinline__ float sigm_fast(float x) {
    return __builtin_amdgcn_rcpf(1.f + __expf(-x));
}
__device__ __forceinline__ float tanh_fast(float x) {
    return 1.f - 2.f * __builtin_amdgcn_rcpf(1.f + __expf(2.f * x));
}

// ---------------- weight prep ----------------
__global__ void transpose_wih_kernel(const float* __restrict__ wih, float* __restrict__ wiht) {
    int g = blockIdx.x;          // 768
    int c = threadIdx.x;         // 256
    wiht[c * 768 + g] = wih[g * 256 + c];
}

// conv2 weights -> MFMA B-fragment order (fp16). Layout HW-verified (R4-R6).
__global__ __launch_bounds__(256) void pack_w2_kernel(const float* __restrict__ w2, f16* __restrict__ w2p) {
    int e = blockIdx.x * 256 + threadIdx.x;     // grid 800 -> 204800 entries
    int lane = e & 63;
    int r1 = e >> 6;
    int ntile = r1 & 15;
    int r2 = r1 >> 4;
    int cs4 = r2 & 3;
    int r3 = r2 >> 2;
    int cs = r3 & 1;
    int tap = r3 >> 1;                          // 0..24
    int co = ntile * 16 + (lane & 15);
    int ci0 = cs * 128 + cs4 * 32 + (lane >> 4) * 8;
    f16x8 v;
#pragma unroll
    for (int j = 0; j < 8; ++j)
        v[j] = (f16)w2[(size_t)co * 6400 + (ci0 + j) * 25 + tap];
    *(f16x8*)(w2p + (size_t)e * 8) = v;
}

// conv3 weights: only kw in {1,2,3} touch the W=2 input -> 15 taps.
__global__ __launch_bounds__(256) void pack_w3_kernel(const float* __restrict__ w3, f16* __restrict__ w3p) {
    int e = blockIdx.x * 256 + threadIdx.x;     // grid 480 -> 122880 entries
    int lane = e & 63;
    int r1 = e >> 6;
    int ntile = r1 & 15;
    int r2 = r1 >> 4;
    int cs4 = r2 & 3;
    int r3 = r2 >> 2;
    int cs = r3 & 1;
    int tap = r3 >> 1;                          // 0..14
    int kh = tap / 3, kw = tap % 3 + 1;
    int co = ntile * 16 + (lane & 15);
    int ci0 = cs * 128 + cs4 * 32 + (lane >> 4) * 8;
    f16x8 v;
#pragma unroll
    for (int j = 0; j < 8; ++j)
        v[j] = (f16)w3[(size_t)co * 6400 + (ci0 + j) * 25 + kh * 5 + kw];
    *(f16x8*)(w3p + (size_t)e * 8) = v;
}

// w_hh -> B-fragment order: entry e = (kf*48 + tile)*64 + lane.
__global__ __launch_bounds__(256) void pack_whh_kernel(const float* __restrict__ whh, f16* __restrict__ whhp) {
    int e = blockIdx.x * 256 + threadIdx.x;     // grid 96 -> 24576 entries
    int lane = e & 63;
    int r1 = e >> 6;                            // 0..383
    int tile = r1 % 48, kf = r1 / 48;
    int g = tile * 16 + (lane & 15);
    int k0 = kf * 32 + (lane >> 4) * 8;
    f16x8 v;
#pragma unroll
    for (int j = 0; j < 8; ++j)
        v[j] = (f16)whh[(size_t)g * HH + k0 + j];
    *(f16x8*)(whhp + (size_t)e * 8) = v;
}

// w_cls -> B-fragment order: entry e = kf*64 + lane; B[k=c][n=nb].
__global__ void pack_wcls_kernel(const float* __restrict__ wcls, f16* __restrict__ wclsp) {
    int e = threadIdx.x;                        // 512
    int lane = e & 63, kf = e >> 6;
    int nb = lane & 15;
    int c0 = kf * 32 + (lane >> 4) * 8;
    f16x8 v;
#pragma unroll
    for (int j = 0; j < 8; ++j)
        v[j] = (f16)wcls[nb * HH + c0 + j];
    *(f16x8*)(wclsp + (size_t)e * 8) = v;
}

// ---------------- conv block 1 (fp32, unchanged) ----------------
__global__ __launch_bounds__(256) void conv1_kernel(
    const float* __restrict__ x, const float* __restrict__ w1,
    const float* __restrict__ b1, const float* __restrict__ g1,
    const float* __restrict__ bt1, const float* __restrict__ m1,
    const float* __restrict__ v1, float* __restrict__ out1) {
    int h = blockIdx.x;          // 512
    int b = blockIdx.y;          // 16
    int c = threadIdx.x;         // 256
    __shared__ float xs[5][44];
    int t = threadIdx.x;
    if (t < 220) {
        int rr = t / 44, cc = t % 44;
        int hh = h + rr - 2, ww = cc - 2;
        float v = 0.f;
        if (hh >= 0 && hh < TT && ww >= 0 && ww < FF) v = x[(b * TT + hh) * FF + ww];
        xs[rr][cc] = v;
    }
    __syncthreads();
    float wr[25];
#pragma unroll
    for (int i = 0; i < 25; ++i) wr[i] = w1[c * 25 + i];
    float sc = g1[c] * rsqrtf(v1[c] + 1e-5f);
    float sh = (b1[c] - m1[c]) * sc + bt1[c];
    float conv[40];
#pragma unroll
    for (int w = 0; w < 40; ++w) conv[w] = 0.f;
#pragma unroll
    for (int kh = 0; kh < 5; ++kh) {
        float rr[44];
#pragma unroll
        for (int i = 0; i < 44; ++i) rr[i] = xs[kh][i];
#pragma unroll
        for (int kw = 0; kw < 5; ++kw) {
            float wv = wr[kh * 5 + kw];
#pragma unroll
            for (int w = 0; w < 40; ++w) conv[w] += rr[w + kw] * wv;
        }
    }
    float* op = out1 + (((size_t)(b * TT + h) * CC) + c) * 8;
#pragma unroll
    for (int j = 0; j < 8; ++j) {
        float m = 0.f;
#pragma unroll
        for (int p = 0; p < 5; ++p) m = fmaxf(m, conv[j * 5 + p] * sc + sh);
        op[j] = m;
    }
}

// ---------------- conv block 2: fp16 MFMA implicit GEMM (proven) ----------------
__global__ __launch_bounds__(256) void conv2_mfma_kernel(
    const float* __restrict__ in, const f16* __restrict__ w2p,
    const float* __restrict__ b2, const float* __restrict__ g2,
    const float* __restrict__ bt2, const float* __restrict__ m2,
    const float* __restrict__ v2, float* __restrict__ out2) {
    int htile = blockIdx.x;                 // 64
    int b = blockIdx.y;                     // 16
    int h0 = htile * 8;
    int t = threadIdx.x;
    int lane = t & 63, wid = t >> 6;
    int m16 = lane & 15, kq = lane >> 4;

    __shared__ f16 lds_a[12 * 12 * 136];    // 39168 B

#pragma unroll
    for (int i = 0; i < 39; ++i) {
        int idx = t + i * 256;
        if (idx < 9792) ((unsigned*)lds_a)[idx] = 0u;
    }
    __syncthreads();

    f32x4 acc[4][4];
#pragma unroll
    for (int mf = 0; mf < 4; ++mf)
#pragma unroll
        for (int nf = 0; nf < 4; ++nf) acc[mf][nf] = (f32x4)(0.f);

    for (int cs = 0; cs < 2; ++cs) {
        if (cs) __syncthreads();
#pragma unroll
        for (int i = 0; i < 2; ++i) {
            int qq = t + i * 256;
            if (qq < 384) {
                int row = qq >> 5, ciq = qq & 31;
                int hp = h0 - 2 + row;
                float fv[32];
                if (hp >= 0 && hp < TT) {
                    const float4* src = (const float4*)(in + (((size_t)(b * TT + hp) * CC) + cs * 128 + ciq * 4) * 8);
#pragma unroll
                    for (int cc = 0; cc < 4; ++cc) {
                        float4 u0 = src[cc * 2], u1 = src[cc * 2 + 1];
                        fv[cc * 8 + 0] = u0.x; fv[cc * 8 + 1] = u0.y; fv[cc * 8 + 2] = u0.z; fv[cc * 8 + 3] = u0.w;
                        fv[cc * 8 + 4] = u1.x; fv[cc * 8 + 5] = u1.y; fv[cc * 8 + 6] = u1.z; fv[cc * 8 + 7] = u1.w;
                    }
                } else {
#pragma unroll
                    for (int z = 0; z < 32; ++z) fv[z] = 0.f;
                }
#pragma unroll
                for (int w = 0; w < 8; ++w) {
                    f16x4 hv = { (f16)fv[0 * 8 + w], (f16)fv[1 * 8 + w], (f16)fv[2 * 8 + w], (f16)fv[3 * 8 + w] };
                    *(f16x4*)&lds_a[row * 1632 + (w + 2) * 136 + ciq * 4] = hv;
                }
            }
        }
        __syncthreads();
        for (int kh = 0; kh < 5; ++kh) {
#pragma unroll
            for (int kw = 0; kw < 5; ++kw) {
                int tap = kh * 5 + kw;
#pragma unroll
                for (int cs4 = 0; cs4 < 4; ++cs4) {
                    f16x8 af[4];
#pragma unroll
                    for (int mf = 0; mf < 4; ++mf) {
                        int m = mf * 16 + m16;
                        int row = (m >> 3) + kh;
                        int wp = (m & 7) + kw;
                        af[mf] = *(const f16x8*)&lds_a[row * 1632 + wp * 136 + cs4 * 32 + kq * 8];
                    }
                    const f16x8* bp = (const f16x8*)w2p
                        + ((size_t)(((tap * 2 + cs) * 4 + cs4) * 16 + wid * 4) * 64 + lane);
#pragma unroll
                    for (int nf = 0; nf < 4; ++nf) {
                        f16x8 bf = bp[nf * 64];
#pragma unroll
                        for (int mf = 0; mf < 4; ++mf)
                            acc[mf][nf] = __builtin_amdgcn_mfma_f32_16x16x32_f16(af[mf], bf, acc[mf][nf], 0, 0, 0);
                    }
                }
            }
        }
    }

#pragma unroll
    for (int nf = 0; nf < 4; ++nf) {
        int co = wid * 64 + nf * 16 + m16;
        float sc = g2[co] * rsqrtf(v2[co] + 1e-5f);
        float sh = (b2[co] - m2[co]) * sc + bt2[co];
#pragma unroll
        for (int mf = 0; mf < 4; ++mf) {
            f32x4 v = acc[mf][nf];
            float p = 0.f;
            p = fmaxf(p, v[0] * sc + sh);
            p = fmaxf(p, v[1] * sc + sh);
            p = fmaxf(p, v[2] * sc + sh);
            p = fmaxf(p, v[3] * sc + sh);
            int dh = mf * 2 + (kq >> 1);
            int wout = kq & 1;
            out2[(((size_t)(b * TT + h0 + dh) * CC) + co) * 2 + wout] = p;
        }
    }
}

// ---------------- conv block 3: fp16 MFMA implicit GEMM (proven) ----------------
__global__ __launch_bounds__(256) void conv3_mfma_kernel(
    const float* __restrict__ in, const f16* __restrict__ w3p,
    const float* __restrict__ b3, const float* __restrict__ g3,
    const float* __restrict__ bt3, const float* __restrict__ m3,
    const float* __restrict__ v3, float* __restrict__ out3) {
    int htile = blockIdx.x;                 // 32
    int b = blockIdx.y;                     // 16
    int h0 = htile * 16;
    int t = threadIdx.x;
    int lane = t & 63, wid = t >> 6;
    int m16 = lane & 15, quad = lane >> 4;
    int rb = m16 >> 1, wv = m16 & 1;

    __shared__ f16 lds_a[20 * 6 * 136];     // 32640 B

    for (int i = t; i < 8160; i += 256) ((unsigned*)lds_a)[i] = 0u;
    __syncthreads();

    f32x4 acc[2][4];
#pragma unroll
    for (int mf = 0; mf < 2; ++mf)
#pragma unroll
        for (int nf = 0; nf < 4; ++nf) acc[mf][nf] = (f32x4)(0.f);

    for (int cs = 0; cs < 2; ++cs) {
        if (cs) __syncthreads();
#pragma unroll
        for (int i = 0; i < 3; ++i) {
            int qq = t + i * 256;
            if (qq < 640) {
                int row = qq >> 5, ciq = qq & 31;
                int hp = h0 - 2 + row;
                if (hp >= 0 && hp < TT) {
                    const float4* src = (const float4*)(in + (((size_t)(b * TT + hp) * CC) + cs * 128 + ciq * 4) * 2);
                    float4 u0 = src[0], u1 = src[1];
                    f16x4 h0v = { (f16)u0.x, (f16)u0.z, (f16)u1.x, (f16)u1.z };
                    f16x4 h1v = { (f16)u0.y, (f16)u0.w, (f16)u1.y, (f16)u1.w };
                    *(f16x4*)&lds_a[row * 816 + 2 * 136 + ciq * 4] = h0v;
                    *(f16x4*)&lds_a[row * 816 + 3 * 136 + ciq * 4] = h1v;
                }
            }
        }
        __syncthreads();
        for (int kh = 0; kh < 5; ++kh) {
#pragma unroll
            for (int kw3 = 0; kw3 < 3; ++kw3) {
                int tap = kh * 3 + kw3;
#pragma unroll
                for (int cs4 = 0; cs4 < 4; ++cs4) {
                    f16x8 af[2];
#pragma unroll
                    for (int mf = 0; mf < 2; ++mf) {
                        int row = mf * 8 + rb + kh;
                        int wp = wv + kw3 + 1;
                        af[mf] = *(const f16x8*)&lds_a[row * 816 + wp * 136 + cs4 * 32 + quad * 8];
                    }
                    const f16x8* bp = (const f16x8*)w3p
                        + ((size_t)(((tap * 2 + cs) * 4 + cs4) * 16 + wid * 4) * 64 + lane);
#pragma unroll
                    for (int nf = 0; nf < 4; ++nf) {
                        f16x8 bf = bp[nf * 64];
#pragma unroll
                        for (int mf = 0; mf < 2; ++mf)
                            acc[mf][nf] = __builtin_amdgcn_mfma_f32_16x16x32_f16(af[mf], bf, acc[mf][nf], 0, 0, 0);
                    }
                }
            }
        }
    }

#pragma unroll
    for (int nf = 0; nf < 4; ++nf) {
        int co = wid * 64 + nf * 16 + m16;
        float sc = g3[co] * rsqrtf(v3[co] + 1e-5f);
        float sh = (b3[co] - m3[co]) * sc + bt3[co];
#pragma unroll
        for (int mf = 0; mf < 2; ++mf) {
            f32x4 v = acc[mf][nf];
            float p0 = fmaxf(0.f, fmaxf(v[0], v[1]) * sc + sh);
            p0 = fmaxf(p0, fmaxf(0.f, fminf(v[0], v[1]) * sc + sh));
            float p1 = fmaxf(0.f, fmaxf(v[2], v[3]) * sc + sh);
            p1 = fmaxf(p1, fmaxf(0.f, fminf(v[2], v[3]) * sc + sh));
            int h = h0 + mf * 8 + quad * 2;
            out3[((size_t)(b * TT + h) * CC) + co] = p0;
            out3[((size_t)(b * TT + h + 1) * CC) + co] = p1;
        }
    }
}

// ---------------- gi_all GEMM -> fp16 output [s][b][768] ----------------
__global__ __launch_bounds__(256) void gi_kernel(
    const float* __restrict__ feats, const float* __restrict__ wiht,
    const float* __restrict__ bih, f16* __restrict__ gih) {
    int bt0 = blockIdx.x * 16;
    int g = blockIdx.y * 256 + threadIdx.x;
    float acc[16];
    float bv = bih[g];
#pragma unroll
    for (int i = 0; i < 16; ++i) acc[i] = bv;
    for (int c = 0; c < CC; ++c) {
        float wv = wiht[c * GG + g];
#pragma unroll
        for (int i = 0; i < 16; ++i) acc[i] += feats[(size_t)(bt0 + i) * CC + c] * wv;
    }
#pragma unroll
    for (int i = 0; i < 16; ++i) {
        int bt = bt0 + i;
        int b = bt >> 9, s = bt & 511;
        gih[((size_t)s * 16 + b) * GG + g] = (f16)acc[i];
    }
}

// ---------------- GRU scan: register-resident weights (asm-pinned) ----------------
// 512 threads = 8 waves @ 2 waves/SIMD (256-VGPR budget). Wave w owns gate columns
// w*32..w*32+31: 6 B-tiles = 192 VGPRs pinned via asm so the compiler CANNOT
// rematerialize the loads inside the loop. gi[s] is prefetched into an LDS double
// buffer with global_load_lds (zero VGPR cost); drained by B1's implicit vmcnt(0).
// h history dumped to hsave (fp16); classifier runs as a separate parallel kernel.
__global__ __launch_bounds__(512, 2) void gru_mfma_kernel(
    const f16* __restrict__ gih, const f16* __restrict__ whhp,
    const float* __restrict__ bhh, f16* __restrict__ hsave) {
    int t = threadIdx.x;
    int w = t >> 6, lane = t & 63;        // w = 0..7
    int n16 = lane & 15, quad = lane >> 4;
    __shared__ f16 hA[16 * 264];          // [b][k] fp16 A-copy of h
    __shared__ f16 gibuf[2][BB * GG];     // 2 x 24 KB gi slices

    for (int i = t; i < 16 * 264; i += 512) hA[i] = (f16)0.f;

    // preload + PIN the 6 weight tiles per wave (192 VGPRs)
    f16x8 wfrag[8][6];
#pragma unroll
    for (int kf = 0; kf < 8; ++kf)
#pragma unroll
        for (int i = 0; i < 6; ++i) {
            int g = i >> 1, p = i & 1;
            wfrag[kf][i] = ((const f16x8*)whhp)[(size_t)(kf * 48 + g * 16 + w * 2 + p) * 64 + lane];
        }
#pragma unroll
    for (int kf = 0; kf < 8; ++kf)
#pragma unroll
        for (int i = 0; i < 6; ++i)
            asm volatile("" : "+v"(wfrag[kf][i]));   // opaque: cannot be re-loaded

    int c0 = w * 32 + n16, c1 = c0 + 16;
    float bh[3][2];
#pragma unroll
    for (int g = 0; g < 3; ++g) { bh[g][0] = bhh[g * HH + c0]; bh[g][1] = bhh[g * HH + c1]; }
    float hold[2][4] = {{0.f, 0.f, 0.f, 0.f}, {0.f, 0.f, 0.f, 0.f}};

    // prefetch gi[0] into buffer 0 (wave w copies 3 x 1KB chunks)
#pragma unroll
    for (int i = 0; i < 3; ++i) {
        int chunk = w * 3 + i;
        __builtin_amdgcn_global_load_lds(
            (const __attribute__((address_space(1))) void*)(gih + chunk * 512 + lane * 8),
            (__attribute__((address_space(3))) void*)(&gibuf[0][chunk * 512]),
            16, 0, 0);
    }
    __syncthreads();    // drains vmcnt+lgkm: gibuf[0] + hA ready

    for (int s = 0; s < TT; ++s) {
        // issue next step's gi prefetch (completes by B1's implicit vmcnt(0))
        if (s + 1 < TT) {
            const f16* src = gih + (size_t)(s + 1) * (BB * GG);
            f16* dst = &gibuf[(s + 1) & 1][0];
#pragma unroll
            for (int i = 0; i < 3; ++i) {
                int chunk = w * 3 + i;
                __builtin_amdgcn_global_load_lds(
                    (const __attribute__((address_space(1))) void*)(src + chunk * 512 + lane * 8),
                    (__attribute__((address_space(3))) void*)(dst + chunk * 512),
                    16, 0, 0);
            }
        }

        f32x4 acc[3][2];
#pragma unroll
        for (int g = 0; g < 3; ++g) { acc[g][0] = (f32x4)(0.f); acc[g][1] = (f32x4)(0.f); }
#pragma unroll
        for (int kf = 0; kf < 8; ++kf) {
            f16x8 af = *(const f16x8*)&hA[n16 * 264 + kf * 32 + quad * 8];
#pragma unroll
            for (int i = 0; i < 6; ++i)
                acc[i >> 1][i & 1] = __builtin_amdgcn_mfma_f32_16x16x32_f16(af, wfrag[kf][i], acc[i >> 1][i & 1], 0, 0, 0);
        }

        const f16* gp = &gibuf[s & 1][0];
#pragma unroll
        for (int r = 0; r < 4; ++r) {
            int b = quad * 4 + r;
            const f16* gb = gp + b * GG;
#pragma unroll
            for (int p = 0; p < 2; ++p) {
                int c = p ? c1 : c0;
                float rr = sigm_fast((float)gb[c] + bh[0][p] + acc[0][p][r]);
                float zz = sigm_fast((float)gb[HH + c] + bh[1][p] + acc[1][p][r]);
                float nn = tanh_fast((float)gb[2 * HH + c] + rr * (bh[2][p] + acc[2][p][r]));
                hold[p][r] = (1.f - zz) * nn + zz * hold[p][r];
            }
        }
        __syncthreads();                  // B1: hA reads + gibuf prefetch drained
#pragma unroll
        for (int r = 0; r < 4; ++r) {
            int b = quad * 4 + r;
            f16 h0v = (f16)hold[0][r], h1v = (f16)hold[1][r];
            hA[b * 264 + c0] = h0v;
            hA[b * 264 + c1] = h1v;
            hsave[((size_t)s * 16 + b) * 256 + c0] = h0v;
            hsave[((size_t)s * 16 + b) * 256 + c1] = h1v;
        }
        __syncthreads();                  // B2: updated h visible
    }
}

// ---------------- classifier: [8192 bt x 256] @ [256 x 16], MFMA ----------------
__global__ __launch_bounds__(256) void cls_kernel(
    const f16* __restrict__ hsave, const f16* __restrict__ wclsp,
    const float* __restrict__ bcls, float* __restrict__ out) {
    int s = blockIdx.x * 4 + (threadIdx.x >> 6);   // grid 128, one s per wave
    int lane = threadIdx.x & 63;
    int n16 = lane & 15, quad = lane >> 4;
    f32x4 ac = (f32x4)(0.f);
#pragma unroll
    for (int kf = 0; kf < 8; ++kf) {
        f16x8 af = *(const f16x8*)&hsave[((size_t)s * 16 + n16) * 256 + kf * 32 + quad * 8];
        f16x8 bf = ((const f16x8*)wclsp)[kf * 64 + lane];
        ac = __builtin_amdgcn_mfma_f32_16x16x32_f16(af, bf, ac, 0, 0, 0);
    }
    float bc = bcls[n16];
#pragma unroll
    for (int r = 0; r < 4; ++r)
        out[((size_t)(quad * 4 + r) * TT + s) * NB + n16] = ac[r] + bc;
}

extern "C" void kernel_launch(void* const* d_in, const int* in_sizes, int n_in,
                              void* d_out, int out_size, void* d_ws, size_t ws_size,
                              hipStream_t stream) {
    const float* x    = (const float*)d_in[0];
    const float* w1   = (const float*)d_in[1];
    const float* b1   = (const float*)d_in[2];
    const float* g1   = (const float*)d_in[3];
    const float* bt1  = (const float*)d_in[4];
    const float* m1   = (const float*)d_in[5];
    const float* v1   = (const float*)d_in[6];
    const float* w2   = (const float*)d_in[7];
    const float* b2   = (const float*)d_in[8];
    const float* g2   = (const float*)d_in[9];
    const float* bt2  = (const float*)d_in[10];
    const float* m2   = (const float*)d_in[11];
    const float* v2   = (const float*)d_in[12];
    const float* w3   = (const float*)d_in[13];
    const float* b3   = (const float*)d_in[14];
    const float* g3   = (const float*)d_in[15];
    const float* bt3  = (const float*)d_in[16];
    const float* m3   = (const float*)d_in[17];
    const float* v3   = (const float*)d_in[18];
    const float* wih  = (const float*)d_in[19];
    const float* whh  = (const float*)d_in[20];
    const float* bih  = (const float*)d_in[21];
    const float* bhh  = (const float*)d_in[22];
    const float* wcls = (const float*)d_in[23];
    const float* bcls = (const float*)d_in[24];

    float* ws   = (float*)d_ws;
    float* out1 = ws + O_OUT1;
    float* out2 = ws + O_OUT2;
    float* out3 = ws + O_OUT3;
    f16*   gih  = (f16*)(ws + O_GI);       // aliases out1 (dead after conv2)
    f16*   w2p  = (f16*)(ws + O_W2P);
    f16*   w3p  = (f16*)(ws + O_W3P);
    f16*   wclsp = (f16*)(ws + O_W3P) + 983040;
    float* wiht = ws + O_WIHT;
    f16*   whhp = (f16*)(ws + O_WHHP);     // aliases out2 (dead after conv3)
    f16*   hsave = (f16*)(ws + O_OUT3);    // aliases out3 (dead after gi_kernel)
    float* fout = (float*)d_out;

    // weight prep
    pack_w2_kernel<<<800, 256, 0, stream>>>(w2, w2p);
    pack_w3_kernel<<<480, 256, 0, stream>>>(w3, w3p);
    pack_wcls_kernel<<<1, 512, 0, stream>>>(wcls, wclsp);
    transpose_wih_kernel<<<768, 256, 0, stream>>>(wih, wiht);

    // conv stack
    conv1_kernel<<<dim3(512, 16), 256, 0, stream>>>(x, w1, b1, g1, bt1, m1, v1, out1);
    conv2_mfma_kernel<<<dim3(64, 16), 256, 0, stream>>>(out1, w2p, b2, g2, bt2, m2, v2, out2);
    conv3_mfma_kernel<<<dim3(32, 16), 256, 0, stream>>>(out2, w3p, b3, g3, bt3, m3, v3, out3);

    // whh fragment-pack into the (now dead) out2 region
    pack_whh_kernel<<<96, 256, 0, stream>>>(whh, whhp);

    // input-to-hidden GEMM -> fp16 gi (out1 region)
    gi_kernel<<<dim3(512, 3), 256, 0, stream>>>(out3, wiht, bih, gih);

    // GRU scan: one block, register-resident weights, h history -> hsave
    gru_mfma_kernel<<<1, 512, 0, stream>>>(gih, whhp, bhh, hsave);

    // classifier over the full h history (parallel, MFMA)
    cls_kernel<<<128, 256, 0, stream>>>(hsave, wclsp, bcls, fout);
}

// Round 8
// 1892.364 us; speedup vs baseline: 7.0792x; 1.0877x over previous
//
#include <hip/hip_runtime.h>
#include <hip/hip_bf16.h>
#include <math.h>

// Problem constants
#define BB 16
#define TT 512
#define FF 40
#define CC 256
#define HH 256
#define GG 768   // 3*H
#define NB 16

typedef _Float16 f16;
typedef __attribute__((ext_vector_type(8))) _Float16 f16x8;
typedef __attribute__((ext_vector_type(4))) _Float16 f16x4;
typedef __attribute__((ext_vector_type(4))) float f32x4;

// Workspace layout (float offsets).
#define O_OUT1 0u                       // [b][h][c][8]  16777216
#define O_GI   0u                       // gi2 [s][g][b] f16, 12 MB (aliases out1, dead after conv2)
#define O_OUT2 16777216u                // [b][h][c][2]  4194304
#define O_WHHP O_OUT2                   // 196608 halves (aliases dead out2)
#define O_OUT3 20971520u                // [b][h][c] 2097152 (feats); hsave f16 aliases after gi_mfma
#define O_W2P  23068672u                // packed fp16 conv2 weights, 1638400 halves
#define O_W3P  24707072u                // packed fp16 conv3 weights, 983040 halves (+ wclsp 4096 halves)
#define O_WIHP 26345472u                // packed fp16 wih, 196608 halves
// total 26542080 floats = 106.2 MB

__device__ __forceinline__ float sigm_fast(float x) {
    return __builtin_amdgcn_rcpf(1.f + __expf(-x));
}
__device__ __forceinline__ float tanh_fast(float x) {
    return 1.f - 2.f * __builtin_amdgcn_rcpf(1.f + __expf(2.f * x));
}

// ---------------- weight prep ----------------
// conv2 weights -> MFMA B-fragment order (fp16). Layout HW-verified (R4-R7).
__global__ __launch_bounds__(256) void pack_w2_kernel(const float* __restrict__ w2, f16* __restrict__ w2p) {
    int e = blockIdx.x * 256 + threadIdx.x;     // grid 800 -> 204800 entries
    int lane = e & 63;
    int r1 = e >> 6;
    int ntile = r1 & 15;
    int r2 = r1 >> 4;
    int cs4 = r2 & 3;
    int r3 = r2 >> 2;
    int cs = r3 & 1;
    int tap = r3 >> 1;                          // 0..24
    int co = ntile * 16 + (lane & 15);
    int ci0 = cs * 128 + cs4 * 32 + (lane >> 4) * 8;
    f16x8 v;
#pragma unroll
    for (int j = 0; j < 8; ++j)
        v[j] = (f16)w2[(size_t)co * 6400 + (ci0 + j) * 25 + tap];
    *(f16x8*)(w2p + (size_t)e * 8) = v;
}

// conv3 weights: only kw in {1,2,3} touch the W=2 input -> 15 taps.
__global__ __launch_bounds__(256) void pack_w3_kernel(const float* __restrict__ w3, f16* __restrict__ w3p) {
    int e = blockIdx.x * 256 + threadIdx.x;     // grid 480 -> 122880 entries
    int lane = e & 63;
    int r1 = e >> 6;
    int ntile = r1 & 15;
    int r2 = r1 >> 4;
    int cs4 = r2 & 3;
    int r3 = r2 >> 2;
    int cs = r3 & 1;
    int tap = r3 >> 1;                          // 0..14
    int kh = tap / 3, kw = tap % 3 + 1;
    int co = ntile * 16 + (lane & 15);
    int ci0 = cs * 128 + cs4 * 32 + (lane >> 4) * 8;
    f16x8 v;
#pragma unroll
    for (int j = 0; j < 8; ++j)
        v[j] = (f16)w3[(size_t)co * 6400 + (ci0 + j) * 25 + kh * 5 + kw];
    *(f16x8*)(w3p + (size_t)e * 8) = v;
}

// 768x256 matrix -> B-fragment order: entry e = (kf*48 + tile)*64 + lane.
// B[k][g]: g = tile*16 + (lane&15), k = kf*32 + (lane>>4)*8 + j. Used for whh AND wih.
__global__ __launch_bounds__(256) void pack_whh_kernel(const float* __restrict__ whh, f16* __restrict__ whhp) {
    int e = blockIdx.x * 256 + threadIdx.x;     // grid 96 -> 24576 entries
    int lane = e & 63;
    int r1 = e >> 6;                            // 0..383
    int tile = r1 % 48, kf = r1 / 48;
    int g = tile * 16 + (lane & 15);
    int k0 = kf * 32 + (lane >> 4) * 8;
    f16x8 v;
#pragma unroll
    for (int j = 0; j < 8; ++j)
        v[j] = (f16)whh[(size_t)g * HH + k0 + j];
    *(f16x8*)(whhp + (size_t)e * 8) = v;
}

// w_cls -> B-fragment order: entry e = kf*64 + lane; B[k=c][n=nb].
__global__ void pack_wcls_kernel(const float* __restrict__ wcls, f16* __restrict__ wclsp) {
    int e = threadIdx.x;                        // 512
    int lane = e & 63, kf = e >> 6;
    int nb = lane & 15;
    int c0 = kf * 32 + (lane >> 4) * 8;
    f16x8 v;
#pragma unroll
    for (int j = 0; j < 8; ++j)
        v[j] = (f16)wcls[nb * HH + c0 + j];
    *(f16x8*)(wclsp + (size_t)e * 8) = v;
}

// ---------------- conv block 1 (fp32, unchanged) ----------------
__global__ __launch_bounds__(256) void conv1_kernel(
    const float* __restrict__ x, const float* __restrict__ w1,
    const float* __restrict__ b1, const float* __restrict__ g1,
    const float* __restrict__ bt1, const float* __restrict__ m1,
    const float* __restrict__ v1, float* __restrict__ out1) {
    int h = blockIdx.x;          // 512
    int b = blockIdx.y;          // 16
    int c = threadIdx.x;         // 256
    __shared__ float xs[5][44];
    int t = threadIdx.x;
    if (t < 220) {
        int rr = t / 44, cc = t % 44;
        int hh = h + rr - 2, ww = cc - 2;
        float v = 0.f;
        if (hh >= 0 && hh < TT && ww >= 0 && ww < FF) v = x[(b * TT + hh) * FF + ww];
        xs[rr][cc] = v;
    }
    __syncthreads();
    float wr[25];
#pragma unroll
    for (int i = 0; i < 25; ++i) wr[i] = w1[c * 25 + i];
    float sc = g1[c] * rsqrtf(v1[c] + 1e-5f);
    float sh = (b1[c] - m1[c]) * sc + bt1[c];
    float conv[40];
#pragma unroll
    for (int w = 0; w < 40; ++w) conv[w] = 0.f;
#pragma unroll
    for (int kh = 0; kh < 5; ++kh) {
        float rr[44];
#pragma unroll
        for (int i = 0; i < 44; ++i) rr[i] = xs[kh][i];
#pragma unroll
        for (int kw = 0; kw < 5; ++kw) {
            float wv = wr[kh * 5 + kw];
#pragma unroll
            for (int w = 0; w < 40; ++w) conv[w] += rr[w + kw] * wv;
        }
    }
    float* op = out1 + (((size_t)(b * TT + h) * CC) + c) * 8;
#pragma unroll
    for (int j = 0; j < 8; ++j) {
        float m = 0.f;
#pragma unroll
        for (int p = 0; p < 5; ++p) m = fmaxf(m, conv[j * 5 + p] * sc + sh);
        op[j] = m;
    }
}

// ---------------- conv block 2: fp16 MFMA implicit GEMM (proven) ----------------
__global__ __launch_bounds__(256) void conv2_mfma_kernel(
    const float* __restrict__ in, const f16* __restrict__ w2p,
    const float* __restrict__ b2, const float* __restrict__ g2,
    const float* __restrict__ bt2, const float* __restrict__ m2,
    const float* __restrict__ v2, float* __restrict__ out2) {
    int htile = blockIdx.x;                 // 64
    int b = blockIdx.y;                     // 16
    int h0 = htile * 8;
    int t = threadIdx.x;
    int lane = t & 63, wid = t >> 6;
    int m16 = lane & 15, kq = lane >> 4;

    __shared__ f16 lds_a[12 * 12 * 136];    // 39168 B

#pragma unroll
    for (int i = 0; i < 39; ++i) {
        int idx = t + i * 256;
        if (idx < 9792) ((unsigned*)lds_a)[idx] = 0u;
    }
    __syncthreads();

    f32x4 acc[4][4];
#pragma unroll
    for (int mf = 0; mf < 4; ++mf)
#pragma unroll
        for (int nf = 0; nf < 4; ++nf) acc[mf][nf] = (f32x4)(0.f);

    for (int cs = 0; cs < 2; ++cs) {
        if (cs) __syncthreads();
#pragma unroll
        for (int i = 0; i < 2; ++i) {
            int qq = t + i * 256;
            if (qq < 384) {
                int row = qq >> 5, ciq = qq & 31;
                int hp = h0 - 2 + row;
                float fv[32];
                if (hp >= 0 && hp < TT) {
                    const float4* src = (const float4*)(in + (((size_t)(b * TT + hp) * CC) + cs * 128 + ciq * 4) * 8);
#pragma unroll
                    for (int cc = 0; cc < 4; ++cc) {
                        float4 u0 = src[cc * 2], u1 = src[cc * 2 + 1];
                        fv[cc * 8 + 0] = u0.x; fv[cc * 8 + 1] = u0.y; fv[cc * 8 + 2] = u0.z; fv[cc * 8 + 3] = u0.w;
                        fv[cc * 8 + 4] = u1.x; fv[cc * 8 + 5] = u1.y; fv[cc * 8 + 6] = u1.z; fv[cc * 8 + 7] = u1.w;
                    }
                } else {
#pragma unroll
                    for (int z = 0; z < 32; ++z) fv[z] = 0.f;
                }
#pragma unroll
                for (int w = 0; w < 8; ++w) {
                    f16x4 hv = { (f16)fv[0 * 8 + w], (f16)fv[1 * 8 + w], (f16)fv[2 * 8 + w], (f16)fv[3 * 8 + w] };
                    *(f16x4*)&lds_a[row * 1632 + (w + 2) * 136 + ciq * 4] = hv;
                }
            }
        }
        __syncthreads();
        for (int kh = 0; kh < 5; ++kh) {
#pragma unroll
            for (int kw = 0; kw < 5; ++kw) {
                int tap = kh * 5 + kw;
#pragma unroll
                for (int cs4 = 0; cs4 < 4; ++cs4) {
                    f16x8 af[4];
#pragma unroll
                    for (int mf = 0; mf < 4; ++mf) {
                        int m = mf * 16 + m16;
                        int row = (m >> 3) + kh;
                        int wp = (m & 7) + kw;
                        af[mf] = *(const f16x8*)&lds_a[row * 1632 + wp * 136 + cs4 * 32 + kq * 8];
                    }
                    const f16x8* bp = (const f16x8*)w2p
                        + ((size_t)(((tap * 2 + cs) * 4 + cs4) * 16 + wid * 4) * 64 + lane);
#pragma unroll
                    for (int nf = 0; nf < 4; ++nf) {
                        f16x8 bf = bp[nf * 64];
#pragma unroll
                        for (int mf = 0; mf < 4; ++mf)
                            acc[mf][nf] = __builtin_amdgcn_mfma_f32_16x16x32_f16(af[mf], bf, acc[mf][nf], 0, 0, 0);
                    }
                }
            }
        }
    }

#pragma unroll
    for (int nf = 0; nf < 4; ++nf) {
        int co = wid * 64 + nf * 16 + m16;
        float sc = g2[co] * rsqrtf(v2[co] + 1e-5f);
        float sh = (b2[co] - m2[co]) * sc + bt2[co];
#pragma unroll
        for (int mf = 0; mf < 4; ++mf) {
            f32x4 v = acc[mf][nf];
            float p = 0.f;
            p = fmaxf(p, v[0] * sc + sh);
            p = fmaxf(p, v[1] * sc + sh);
            p = fmaxf(p, v[2] * sc + sh);
            p = fmaxf(p, v[3] * sc + sh);
            int dh = mf * 2 + (kq >> 1);
            int wout = kq & 1;
            out2[(((size_t)(b * TT + h0 + dh) * CC) + co) * 2 + wout] = p;
        }
    }
}

// ---------------- conv block 3: fp16 MFMA implicit GEMM (proven) ----------------
__global__ __launch_bounds__(256) void conv3_mfma_kernel(
    const float* __restrict__ in, const f16* __restrict__ w3p,
    const float* __restrict__ b3, const float* __restrict__ g3,
    const float* __restrict__ bt3, const float* __restrict__ m3,
    const float* __restrict__ v3, float* __restrict__ out3) {
    int htile = blockIdx.x;                 // 32
    int b = blockIdx.y;                     // 16
    int h0 = htile * 16;
    int t = threadIdx.x;
    int lane = t & 63, wid = t >> 6;
    int m16 = lane & 15, quad = lane >> 4;
    int rb = m16 >> 1, wv = m16 & 1;

    __shared__ f16 lds_a[20 * 6 * 136];     // 32640 B

    for (int i = t; i < 8160; i += 256) ((unsigned*)lds_a)[i] = 0u;
    __syncthreads();

    f32x4 acc[2][4];
#pragma unroll
    for (int mf = 0; mf < 2; ++mf)
#pragma unroll
        for (int nf = 0; nf < 4; ++nf) acc[mf][nf] = (f32x4)(0.f);

    for (int cs = 0; cs < 2; ++cs) {
        if (cs) __syncthreads();
#pragma unroll
        for (int i = 0; i < 3; ++i) {
            int qq = t + i * 256;
            if (qq < 640) {
                int row = qq >> 5, ciq = qq & 31;
                int hp = h0 - 2 + row;
                if (hp >= 0 && hp < TT) {
                    const float4* src = (const float4*)(in + (((size_t)(b * TT + hp) * CC) + cs * 128 + ciq * 4) * 2);
                    float4 u0 = src[0], u1 = src[1];
                    f16x4 h0v = { (f16)u0.x, (f16)u0.z, (f16)u1.x, (f16)u1.z };
                    f16x4 h1v = { (f16)u0.y, (f16)u0.w, (f16)u1.y, (f16)u1.w };
                    *(f16x4*)&lds_a[row * 816 + 2 * 136 + ciq * 4] = h0v;
                    *(f16x4*)&lds_a[row * 816 + 3 * 136 + ciq * 4] = h1v;
                }
            }
        }
        __syncthreads();
        for (int kh = 0; kh < 5; ++kh) {
#pragma unroll
            for (int kw3 = 0; kw3 < 3; ++kw3) {
                int tap = kh * 3 + kw3;
#pragma unroll
                for (int cs4 = 0; cs4 < 4; ++cs4) {
                    f16x8 af[2];
#pragma unroll
                    for (int mf = 0; mf < 2; ++mf) {
                        int row = mf * 8 + rb + kh;
                        int wp = wv + kw3 + 1;
                        af[mf] = *(const f16x8*)&lds_a[row * 816 + wp * 136 + cs4 * 32 + quad * 8];
                    }
                    const f16x8* bp = (const f16x8*)w3p
                        + ((size_t)(((tap * 2 + cs) * 4 + cs4) * 16 + wid * 4) * 64 + lane);
#pragma unroll
                    for (int nf = 0; nf < 4; ++nf) {
                        f16x8 bf = bp[nf * 64];
#pragma unroll
                        for (int mf = 0; mf < 2; ++mf)
                            acc[mf][nf] = __builtin_amdgcn_mfma_f32_16x16x32_f16(af[mf], bf, acc[mf][nf], 0, 0, 0);
                    }
                }
            }
        }
    }

#pragma unroll
    for (int nf = 0; nf < 4; ++nf) {
        int co = wid * 64 + nf * 16 + m16;
        float sc = g3[co] * rsqrtf(v3[co] + 1e-5f);
        float sh = (b3[co] - m3[co]) * sc + bt3[co];
#pragma unroll
        for (int mf = 0; mf < 2; ++mf) {
            f32x4 v = acc[mf][nf];
            float p0 = fmaxf(0.f, fmaxf(v[0], v[1]) * sc + sh);
            p0 = fmaxf(p0, fmaxf(0.f, fminf(v[0], v[1]) * sc + sh));
            float p1 = fmaxf(0.f, fmaxf(v[2], v[3]) * sc + sh);
            p1 = fmaxf(p1, fmaxf(0.f, fminf(v[2], v[3]) * sc + sh));
            int h = h0 + mf * 8 + quad * 2;
            out3[((size_t)(b * TT + h) * CC) + co] = p0;
            out3[((size_t)(b * TT + h + 1) * CC) + co] = p1;
        }
    }
}

// ---------------- gi GEMM via MFMA -> gi2 [s][g][b] fp16 ----------------
// [8192 bt x 256 c] @ [256 c x 768 g]. Block = 16 bt (one b, 16 consecutive s),
// 4 waves; wave w covers g-range w*192..+192 (12 tiles). Grid 512.
__global__ __launch_bounds__(256) void gi_mfma_kernel(
    const float* __restrict__ feats, const f16* __restrict__ wihp,
    const float* __restrict__ bih, f16* __restrict__ gi2) {
    int bt0 = blockIdx.x * 16;
    int b0 = bt0 >> 9, s0 = bt0 & 511;
    int t = threadIdx.x;
    int w = t >> 6, lane = t & 63;
    int m16 = lane & 15, quad = lane >> 4;
    f32x4 acc[12];
#pragma unroll
    for (int i = 0; i < 12; ++i) acc[i] = (f32x4)(0.f);
#pragma unroll
    for (int kf = 0; kf < 8; ++kf) {
        const float* ap = feats + ((size_t)(bt0 + m16) * CC + kf * 32 + quad * 8);
        float4 u0 = *(const float4*)ap, u1 = *(const float4*)(ap + 4);
        f16x8 af = { (f16)u0.x, (f16)u0.y, (f16)u0.z, (f16)u0.w,
                     (f16)u1.x, (f16)u1.y, (f16)u1.z, (f16)u1.w };
#pragma unroll
        for (int nt = 0; nt < 12; ++nt) {
            f16x8 bf = ((const f16x8*)wihp)[(size_t)(kf * 48 + w * 12 + nt) * 64 + lane];
            acc[nt] = __builtin_amdgcn_mfma_f32_16x16x32_f16(af, bf, acc[nt], 0, 0, 0);
        }
    }
#pragma unroll
    for (int nt = 0; nt < 12; ++nt) {
        int g = (w * 12 + nt) * 16 + m16;      // D col = lane&15
        float bv = bih[g];
#pragma unroll
        for (int r = 0; r < 4; ++r) {
            int s = s0 + quad * 4 + r;          // D row = quad*4+r
            gi2[((size_t)s * GG + g) * 16 + b0] = (f16)(acc[nt][r] + bv);
        }
    }
}

// ---------------- GRU scan: 16 waves, pinned weights, 1 barrier/step ----------------
// 1024 threads = 16 waves (4/SIMD). Wave w owns gate cols w*16..w*16+15: 3 pinned
// B-tiles (r,z,n) = 96 regs. hA double-buffered -> ONE barrier/step. gi read as
// 3 coalesced 8-B global loads/thread from gi2[s][g][b]. hsave stores deferred one
// step so the pre-barrier vmcnt drain never waits on them.
__global__ __launch_bounds__(1024) void gru_mfma_kernel(
    const f16* __restrict__ gi2, const f16* __restrict__ whhp,
    const float* __restrict__ bhh, f16* __restrict__ hsave) {
    int t = threadIdx.x;
    int w = t >> 6, lane = t & 63;        // w = 0..15
    int n16 = lane & 15, quad = lane >> 4;
    __shared__ f16 hA[2][16 * 264];       // [parity][b][k], pad 8 halves

    for (int i = t; i < 2 * 16 * 264; i += 1024) ((f16*)hA)[i] = (f16)0.f;

    // preload + PIN 3 weight tiles (96 VGPRs/AGPRs)
    f16x8 wfrag[8][3];
#pragma unroll
    for (int kf = 0; kf < 8; ++kf)
#pragma unroll
        for (int g = 0; g < 3; ++g)
            wfrag[kf][g] = ((const f16x8*)whhp)[(size_t)(kf * 48 + g * 16 + w) * 64 + lane];
#pragma unroll
    for (int kf = 0; kf < 8; ++kf)
#pragma unroll
        for (int g = 0; g < 3; ++g)
            asm volatile("" : "+v"(wfrag[kf][g]));   // opaque: cannot be re-loaded

    int c = w * 16 + n16;
    float bh0 = bhh[c], bh1 = bhh[HH + c], bh2 = bhh[2 * HH + c];
    float hold[4] = {0.f, 0.f, 0.f, 0.f};
    f16 hprev[4];
    __syncthreads();

    for (int s = 0; s < TT; ++s) {
        // gi loads for this step (drained by the end-of-step barrier at the latest)
        f16x4 gic[3];
#pragma unroll
        for (int j = 0; j < 3; ++j)
            gic[j] = *(const f16x4*)&gi2[((size_t)s * GG + c + j * HH) * 16 + quad * 4];

        // deferred hsave store for step s-1 (full step of drain slack)
        if (s > 0) {
#pragma unroll
            for (int r = 0; r < 4; ++r)
                hsave[((size_t)(s - 1) * 16 + (quad * 4 + r)) * HH + c] = hprev[r];
        }

        f32x4 acc[3];
#pragma unroll
        for (int g = 0; g < 3; ++g) acc[g] = (f32x4)(0.f);
#pragma unroll
        for (int kf = 0; kf < 8; ++kf) {
            f16x8 af = *(const f16x8*)&hA[s & 1][n16 * 264 + kf * 32 + quad * 8];
#pragma unroll
            for (int g = 0; g < 3; ++g)
                acc[g] = __builtin_amdgcn_mfma_f32_16x16x32_f16(af, wfrag[kf][g], acc[g], 0, 0, 0);
        }

#pragma unroll
        for (int r = 0; r < 4; ++r) {
            float rr = sigm_fast((float)gic[0][r] + bh0 + acc[0][r]);
            float zz = sigm_fast((float)gic[1][r] + bh1 + acc[1][r]);
            float nn = tanh_fast((float)gic[2][r] + rr * (bh2 + acc[2][r]));
            hold[r] = nn + zz * (hold[r] - nn);
        }

        int nb = (s + 1) & 1;
#pragma unroll
        for (int r = 0; r < 4; ++r) {
            f16 hv = (f16)hold[r];
            hprev[r] = hv;
            hA[nb][(quad * 4 + r) * 264 + c] = hv;
        }
        __syncthreads();                  // writes(s) visible; all reads(s) done
    }
    // final hsave store (step TT-1)
#pragma unroll
    for (int r = 0; r < 4; ++r)
        hsave[((size_t)(TT - 1) * 16 + (quad * 4 + r)) * HH + c] = hprev[r];
}

// ---------------- classifier: [8192 bt x 256] @ [256 x 16], MFMA ----------------
__global__ __launch_bounds__(256) void cls_kernel(
    const f16* __restrict__ hsave, const f16* __restrict__ wclsp,
    const float* __restrict__ bcls, float* __restrict__ out) {
    int s = blockIdx.x * 4 + (threadIdx.x >> 6);   // grid 128, one s per wave
    int lane = threadIdx.x & 63;
    int n16 = lane & 15, quad = lane >> 4;
    f32x4 ac = (f32x4)(0.f);
#pragma unroll
    for (int kf = 0; kf < 8; ++kf) {
        f16x8 af = *(const f16x8*)&hsave[((size_t)s * 16 + n16) * 256 + kf * 32 + quad * 8];
        f16x8 bf = ((const f16x8*)wclsp)[kf * 64 + lane];
        ac = __builtin_amdgcn_mfma_f32_16x16x32_f16(af, bf, ac, 0, 0, 0);
    }
    float bc = bcls[n16];
#pragma unroll
    for (int r = 0; r < 4; ++r)
        out[((size_t)(quad * 4 + r) * TT + s) * NB + n16] = ac[r] + bc;
}

extern "C" void kernel_launch(void* const* d_in, const int* in_sizes, int n_in,
                              void* d_out, int out_size, void* d_ws, size_t ws_size,
                              hipStream_t stream) {
    const float* x    = (const float*)d_in[0];
    const float* w1   = (const float*)d_in[1];
    const float* b1   = (const float*)d_in[2];
    const float* g1   = (const float*)d_in[3];
    const float* bt1  = (const float*)d_in[4];
    const float* m1   = (const float*)d_in[5];
    const float* v1   = (const float*)d_in[6];
    const float* w2   = (const float*)d_in[7];
    const float* b2   = (const float*)d_in[8];
    const float* g2   = (const float*)d_in[9];
    const float* bt2  = (const float*)d_in[10];
    const float* m2   = (const float*)d_in[11];
    const float* v2   = (const float*)d_in[12];
    const float* w3   = (const float*)d_in[13];
    const float* b3   = (const float*)d_in[14];
    const float* g3   = (const float*)d_in[15];
    const float* bt3  = (const float*)d_in[16];
    const float* m3   = (const float*)d_in[17];
    const float* v3   = (const float*)d_in[18];
    const float* wih  = (const float*)d_in[19];
    const float* whh  = (const float*)d_in[20];
    const float* bih  = (const float*)d_in[21];
    const float* bhh  = (const float*)d_in[22];
    const float* wcls = (const float*)d_in[23];
    const float* bcls = (const float*)d_in[24];

    float* ws   = (float*)d_ws;
    float* out1 = ws + O_OUT1;
    float* out2 = ws + O_OUT2;
    float* out3 = ws + O_OUT3;
    f16*   gi2  = (f16*)(ws + O_GI);       // aliases out1 (dead after conv2)
    f16*   w2p  = (f16*)(ws + O_W2P);
    f16*   w3p  = (f16*)(ws + O_W3P);
    f16*   wclsp = (f16*)(ws + O_W3P) + 983040;
    f16*   wihp = (f16*)(ws + O_WIHP);
    f16*   whhp = (f16*)(ws + O_WHHP);     // aliases out2 (dead after conv3)
    f16*   hsave = (f16*)(ws + O_OUT3);    // aliases out3 (dead after gi_mfma)
    float* fout = (float*)d_out;

    // weight prep
    pack_w2_kernel<<<800, 256, 0, stream>>>(w2, w2p);
    pack_w3_kernel<<<480, 256, 0, stream>>>(w3, w3p);
    pack_wcls_kernel<<<1, 512, 0, stream>>>(wcls, wclsp);
    pack_whh_kernel<<<96, 256, 0, stream>>>(wih, wihp);    // same 768x256 shape

    // conv stack
    conv1_kernel<<<dim3(512, 16), 256, 0, stream>>>(x, w1, b1, g1, bt1, m1, v1, out1);
    conv2_mfma_kernel<<<dim3(64, 16), 256, 0, stream>>>(out1, w2p, b2, g2, bt2, m2, v2, out2);
    conv3_mfma_kernel<<<dim3(32, 16), 256, 0, stream>>>(out2, w3p, b3, g3, bt3, m3, v3, out3);

    // whh fragment-pack into the (now dead) out2 region
    pack_whh_kernel<<<96, 256, 0, stream>>>(whh, whhp);

    // input-to-hidden GEMM via MFMA -> gi2 [s][g][b] fp16 (out1 region)
    gi_mfma_kernel<<<512, 256, 0, stream>>>(out3, wihp, bih, gi2);

    // GRU scan: one block, pinned weights, h history -> hsave
    gru_mfma_kernel<<<1, 1024, 0, stream>>>(gi2, whhp, bhh, hsave);

    // classifier over the full h history (parallel, MFMA)
    cls_kernel<<<128, 256, 0, stream>>>(hsave, wclsp, bcls, fout);
}